// Round 4
// baseline (1059.137 us; speedup 1.0000x reference)
//
#include <hip/hip_runtime.h>
#include <hip/hip_bf16.h>
#include <float.h>

#define N_NODES 100000
#define N_EDGES 1600000
#define HIDDEN 64
#define N_GRAPHS 128
#define NEG_SLOPE 0.2f
#define ETOT (N_EDGES + N_NODES)

#define BSHIFT 10
#define NB ((N_NODES + 1023) >> BSHIFT)   // 98 buckets of 1024 nodes
#define PAIR_CHUNK 8192
#define PAIR_BLOCKS ((N_EDGES + PAIR_CHUNK - 1) / PAIR_CHUNK)  // 196

__device__ __forceinline__ unsigned short f2bf(float f) {
    unsigned u = __float_as_uint(f);
    unsigned r = (u + 0x7FFFu + ((u >> 16) & 1u)) >> 16;  // RNE
    return (unsigned short)r;
}

// ---------------- init: zero bucket counters + pool accumulator ----------------

__global__ void k_init(int* __restrict__ cnt, float* __restrict__ pool_acc) {
    int t = threadIdx.x;
    if (t < NB) cnt[t] = 0;
    if (t < 2 * N_GRAPHS) pool_acc[t] = 0.f;
}

// ---------------- bucketed CSR build ----------------

__global__ __launch_bounds__(256) void k_bucket_hist(const int* __restrict__ dst,
                                                     int* __restrict__ bucket_cnt) {
    __shared__ int h[NB];
    int t = threadIdx.x;
    if (t < NB) h[t] = 0;
    __syncthreads();
    int stride = gridDim.x * blockDim.x;
    for (int e = blockIdx.x * blockDim.x + t; e < N_EDGES; e += stride)
        atomicAdd(&h[dst[e] >> BSHIFT], 1);
    __syncthreads();
    if (t < NB) atomicAdd(&bucket_cnt[t], h[t]);
}

__global__ void k_bucket_scan(const int* __restrict__ bucket_cnt,
                              int* __restrict__ pair_start,
                              int* __restrict__ bucket_next) {
    __shared__ int s[128];
    int t = threadIdx.x;
    int v = (t < NB) ? bucket_cnt[t] : 0;
    s[t] = v;
    __syncthreads();
    for (int off = 1; off < 128; off <<= 1) {
        int u = (t >= off) ? s[t - off] : 0;
        __syncthreads();
        s[t] += u;
        __syncthreads();
    }
    if (t < NB) {
        int ex = s[t] - v;
        pair_start[t] = ex;
        bucket_next[t] = ex;
    }
    if (t == 0) pair_start[NB] = N_EDGES;
}

__global__ __launch_bounds__(256) void k_pair_scatter(
    const int* __restrict__ e0, const int* __restrict__ e1,
    int* __restrict__ bucket_next, int2* __restrict__ pairs)
{
    __shared__ int cnt[NB];
    __shared__ int base[NB];
    int t = threadIdx.x;
    int ebase = blockIdx.x * PAIR_CHUNK;
    int ecount = min(PAIR_CHUNK, N_EDGES - ebase);

    if (t < NB) cnt[t] = 0;
    __syncthreads();
    for (int i = t; i < ecount; i += 256)
        atomicAdd(&cnt[e1[ebase + i] >> BSHIFT], 1);
    __syncthreads();
    if (t < NB) {
        base[t] = atomicAdd(&bucket_next[t], cnt[t]);
        cnt[t] = 0;
    }
    __syncthreads();
    for (int i = t; i < ecount; i += 256) {
        int s = e0[ebase + i];
        int d = e1[ebase + i];
        int b = d >> BSHIFT;
        int idx = atomicAdd(&cnt[b], 1);
        pairs[base[b] + idx] = make_int2(s, d);
    }
}

// One block per bucket: local degree histogram + wave-scan + col scatter in LDS.
// Self loop occupies slot 0 of each row.
__global__ __launch_bounds__(1024) void k_csr_bucket(
    const int2* __restrict__ pairs, const int* __restrict__ pair_start,
    int* __restrict__ rowptr, int* __restrict__ col)
{
    __shared__ int deg[1024];
    __shared__ int excl[1024];
    __shared__ int wsum[16];
    int b = blockIdx.x;
    int t = threadIdx.x;
    int nb = b << BSHIFT;
    int nodes = min(1024, N_NODES - nb);

    deg[t] = (t < nodes) ? 1 : 0;   // self loop
    __syncthreads();
    int p0 = pair_start[b], p1 = pair_start[b + 1];
    for (int i = p0 + t; i < p1; i += 1024)
        atomicAdd(&deg[pairs[i].y - nb], 1);
    __syncthreads();

    int val = deg[t];
    int x = val;
#pragma unroll
    for (int off = 1; off < 64; off <<= 1) {
        int y = __shfl_up(x, off);
        if ((t & 63) >= off) x += y;
    }
    if ((t & 63) == 63) wsum[t >> 6] = x;
    __syncthreads();
    if (t == 0) {
        int s = 0;
#pragma unroll
        for (int i = 0; i < 16; ++i) { int v = wsum[i]; wsum[i] = s; s += v; }
    }
    __syncthreads();
    int ex = x - val + wsum[t >> 6];  // exclusive prefix of local degrees
    excl[t] = ex;

    int colbase = p0 + nb;  // nb == #self-loops in preceding buckets
    if (t < nodes) {
        rowptr[nb + t] = colbase + ex;
        col[colbase + ex] = nb + t;  // self loop at slot 0
    }
    if (b == NB - 1 && t == 0) rowptr[N_NODES] = ETOT;

    deg[t] = 1;  // slot 0 taken by self loop
    __syncthreads();
    for (int i = p0 + t; i < p1; i += 1024) {
        int2 pr = pairs[i];
        int li = pr.y - nb;
        int pos = colbase + excl[li] + atomicAdd(&deg[li], 1);
        col[pos] = pr.x;
    }
}

// ---------------- per-layer GEMM + attention scores ----------------
// hWb (bf16) = h @ W ; s_src = hW @ a_s ; s_dst = hW @ a_d  (scores fp32)

__global__ __launch_bounds__(256) void k_gemm_score(
    const float* __restrict__ h, const int* __restrict__ x,
    const float* __restrict__ embed, const float* __restrict__ W,
    const float* __restrict__ a_s, const float* __restrict__ a_d,
    unsigned short* __restrict__ hWb, float* __restrict__ s_src,
    float* __restrict__ s_dst, int layer0)
{
    __shared__ float Wl[64 * 64];
    __shared__ float hT[64 * 68];  // [k][r], pitch 68
    int t = threadIdx.x;
    int r0 = blockIdx.x * 64;

    for (int i = t; i < 4096; i += 256) Wl[i] = W[i];
    for (int i = t; i < 4096; i += 256) {
        int r = i >> 6, k = i & 63;
        int row = r0 + r;
        float v = 0.f;
        if (row < N_NODES)
            v = layer0 ? embed[x[row] * 64 + k] : h[row * 64 + k];
        hT[k * 68 + r] = v;
    }
    __syncthreads();

    int tcol = t & 15;
    int trow = t >> 4;
    float acc[4][4];
#pragma unroll
    for (int i = 0; i < 4; ++i)
#pragma unroll
        for (int j = 0; j < 4; ++j) acc[i][j] = 0.f;

    for (int k = 0; k < 64; ++k) {
        float4 va = *(const float4*)&hT[k * 68 + trow * 4];
        float4 vb = *(const float4*)&Wl[k * 64 + tcol * 4];
        float a[4] = {va.x, va.y, va.z, va.w};
        float bb[4] = {vb.x, vb.y, vb.z, vb.w};
#pragma unroll
        for (int i = 0; i < 4; ++i)
#pragma unroll
            for (int j = 0; j < 4; ++j) acc[i][j] = fmaf(a[i], bb[j], acc[i][j]);
    }

    float4 as4 = *(const float4*)&a_s[tcol * 4];
    float4 ad4 = *(const float4*)&a_d[tcol * 4];
    float asr[4] = {as4.x, as4.y, as4.z, as4.w};
    float adr[4] = {ad4.x, ad4.y, ad4.z, ad4.w};

#pragma unroll
    for (int i = 0; i < 4; ++i) {
        int row = r0 + trow * 4 + i;
        float ps = 0.f, pd = 0.f;
#pragma unroll
        for (int j = 0; j < 4; ++j) {
            ps = fmaf(acc[i][j], asr[j], ps);
            pd = fmaf(acc[i][j], adr[j], pd);
        }
#pragma unroll
        for (int off = 8; off >= 1; off >>= 1) {
            ps += __shfl_xor(ps, off);
            pd += __shfl_xor(pd, off);
        }
        if (row < N_NODES) {
            ushort4 o;
            o.x = f2bf(acc[i][0]); o.y = f2bf(acc[i][1]);
            o.z = f2bf(acc[i][2]); o.w = f2bf(acc[i][3]);
            *(ushort4*)&hWb[row * 64 + tcol * 4] = o;
            if (tcol == 0) { s_src[row] = ps; s_dst[row] = pd; }
        }
    }
}

// ---------------- attention softmax + aggregation (one wave per dst node) ----------------
// mode 0: out = relu(agg + bias) -> hout
// mode 1 (last layer): project (agg + bias) @ W_out -> atomicAdd into pool_acc[graph]

__global__ __launch_bounds__(256) void k_agg(
    const unsigned short* __restrict__ hWb, const int* __restrict__ col,
    const int* __restrict__ rowptr, const float* __restrict__ s_src,
    const float* __restrict__ s_dst, const float* __restrict__ bias,
    float* __restrict__ hout, int mode,
    const int* __restrict__ batch, const float* __restrict__ W_out,
    float* __restrict__ pool_acc)
{
    __shared__ float2 stash[4][64];  // (alpha, elem-offset bits)
    int wave = threadIdx.x >> 6;
    int lane = threadIdx.x & 63;
    int node = blockIdx.x * 4 + wave;
    if (node >= N_NODES) return;

    int row = rowptr[node];
    int end = rowptr[node + 1];
    int deg = end - row;
    float sdi = s_dst[node];

    if (deg <= 64) {
        int c = 0;
        float e = -FLT_MAX;
        if (lane < deg) {
            c = col[row + lane];
            float ee = s_src[c] + sdi;
            e = (ee >= 0.f) ? ee : NEG_SLOPE * ee;
        }
        float m = e;
#pragma unroll
        for (int off = 32; off >= 1; off >>= 1) m = fmaxf(m, __shfl_xor(m, off));
        float p = (lane < deg) ? __expf(e - m) : 0.f;
        float denom = p;
#pragma unroll
        for (int off = 32; off >= 1; off >>= 1) denom += __shfl_xor(denom, off);
        float inv = 1.f / denom;
        // lanes >= deg stash alpha=0, offset=0 (harmless reads of hWb[0..])
        stash[wave][lane] = make_float2(p * inv, __int_as_float(c * 64));

        int half = lane >> 5;   // which edge of the pair
        int hl = lane & 31;     // feature pair index: features 2*hl, 2*hl+1
        float acc0 = 0.f, acc1 = 0.f;
        int degr = (deg + 7) & ~7;
        for (int j = half; j < degr; j += 8) {
            float2 ac0 = stash[wave][j];
            float2 ac2 = stash[wave][j + 2];
            float2 ac4 = stash[wave][j + 4];
            float2 ac6 = stash[wave][j + 6];
            unsigned v0 = *(const unsigned*)&hWb[__float_as_int(ac0.y) + hl * 2];
            unsigned v2 = *(const unsigned*)&hWb[__float_as_int(ac2.y) + hl * 2];
            unsigned v4 = *(const unsigned*)&hWb[__float_as_int(ac4.y) + hl * 2];
            unsigned v6 = *(const unsigned*)&hWb[__float_as_int(ac6.y) + hl * 2];
            acc0 = fmaf(ac0.x, __uint_as_float(v0 << 16), acc0);
            acc1 = fmaf(ac0.x, __uint_as_float(v0 & 0xFFFF0000u), acc1);
            acc0 = fmaf(ac2.x, __uint_as_float(v2 << 16), acc0);
            acc1 = fmaf(ac2.x, __uint_as_float(v2 & 0xFFFF0000u), acc1);
            acc0 = fmaf(ac4.x, __uint_as_float(v4 << 16), acc0);
            acc1 = fmaf(ac4.x, __uint_as_float(v4 & 0xFFFF0000u), acc1);
            acc0 = fmaf(ac6.x, __uint_as_float(v6 << 16), acc0);
            acc1 = fmaf(ac6.x, __uint_as_float(v6 & 0xFFFF0000u), acc1);
        }
        acc0 += __shfl_xor(acc0, 32);
        acc1 += __shfl_xor(acc1, 32);
        if (half == 0) {
            float2 bb = ((const float2*)bias)[hl];
            float o0 = acc0 + bb.x, o1 = acc1 + bb.y;
            if (mode == 0) {
                o0 = fmaxf(o0, 0.f); o1 = fmaxf(o1, 0.f);
                *(float2*)&hout[node * 64 + hl * 2] = make_float2(o0, o1);
            } else {
                // project features (2*hl, 2*hl+1) onto W_out rows
                float4 w = *(const float4*)&W_out[4 * hl];
                float p0 = fmaf(o0, w.x, o1 * w.z);
                float p1 = fmaf(o0, w.y, o1 * w.w);
#pragma unroll
                for (int off = 16; off >= 1; off >>= 1) {
                    p0 += __shfl_xor(p0, off);
                    p1 += __shfl_xor(p1, off);
                }
                if (hl == 0) {
                    int g = batch[node];
                    atomicAdd(&pool_acc[g * 2], p0);
                    atomicAdd(&pool_acc[g * 2 + 1], p1);
                }
            }
        }
    } else {
        // generic path (deg > 64): statistically never hit
        float m = -FLT_MAX;
        for (int j = row + lane; j < end; j += 64) {
            float ee = s_src[col[j]] + sdi;
            ee = (ee >= 0.f) ? ee : NEG_SLOPE * ee;
            m = fmaxf(m, ee);
        }
#pragma unroll
        for (int off = 32; off >= 1; off >>= 1) m = fmaxf(m, __shfl_xor(m, off));
        float denom = 0.f;
        for (int j = row + lane; j < end; j += 64) {
            float ee = s_src[col[j]] + sdi;
            ee = (ee >= 0.f) ? ee : NEG_SLOPE * ee;
            denom += __expf(ee - m);
        }
#pragma unroll
        for (int off = 32; off >= 1; off >>= 1) denom += __shfl_xor(denom, off);
        float inv = 1.f / denom;
        float acc = 0.f;
        for (int j = row; j < end; ++j) {
            int cc = col[j];
            float ee = s_src[cc] + sdi;
            ee = (ee >= 0.f) ? ee : NEG_SLOPE * ee;
            unsigned hv = hWb[cc * 64 + lane];
            acc = fmaf(__expf(ee - m) * inv, __uint_as_float(hv << 16), acc);
        }
        float o = acc + bias[lane];
        if (mode == 0) {
            o = fmaxf(o, 0.f);
            hout[node * 64 + lane] = o;
        } else {
            float p0 = o * W_out[lane * 2];
            float p1 = o * W_out[lane * 2 + 1];
#pragma unroll
            for (int off = 32; off >= 1; off >>= 1) {
                p0 += __shfl_xor(p0, off);
                p1 += __shfl_xor(p1, off);
            }
            if (lane == 0) {
                int g = batch[node];
                atomicAdd(&pool_acc[g * 2], p0);
                atomicAdd(&pool_acc[g * 2 + 1], p1);
            }
        }
    }
}

// ---------------- head: divide by count, add b_out ----------------

__device__ __forceinline__ int lower_bound_dev(const int* __restrict__ a, int n, int v) {
    int lo = 0, hi = n;
    while (lo < hi) {
        int mid = (lo + hi) >> 1;
        if (a[mid] < v) lo = mid + 1; else hi = mid;
    }
    return lo;
}

__global__ void k_head(const float* __restrict__ pool_acc,
                       const int* __restrict__ batch,
                       const float* __restrict__ b_out,
                       float* __restrict__ out)
{
    int t = threadIdx.x;
    if (t < 2 * N_GRAPHS) {
        int g = t >> 1, c = t & 1;
        int start = lower_bound_dev(batch, N_NODES, g);
        int end = lower_bound_dev(batch, N_NODES, g + 1);
        float cnt = fmaxf((float)(end - start), 1.f);
        out[t] = pool_acc[t] / cnt + b_out[c];
    }
}

// ---------------- launch ----------------

extern "C" void kernel_launch(void* const* d_in, const int* in_sizes, int n_in,
                              void* d_out, int out_size, void* d_ws, size_t ws_size,
                              hipStream_t stream) {
    const int*   x       = (const int*)d_in[0];
    const int*   edge    = (const int*)d_in[1];   // [2][E]
    const int*   batch   = (const int*)d_in[2];
    const float* embed   = (const float*)d_in[3];
    const float* Ws      = (const float*)d_in[4];
    const float* a_srcs  = (const float*)d_in[5];
    const float* a_dsts  = (const float*)d_in[6];
    const float* biases  = (const float*)d_in[7];
    const float* W_out   = (const float*)d_in[8];
    const float* b_out   = (const float*)d_in[9];
    float* out = (float*)d_out;

    char* ws = (char*)d_ws;
    size_t off = 0;
    auto alloc = [&](size_t bytes) -> void* {
        void* p = ws + off;
        off += (bytes + 255) & ~(size_t)255;
        return p;
    };
    float*          hbuf0  = (float*)alloc((size_t)N_NODES * 64 * sizeof(float));  // layer io fp32
    unsigned short* hWb    = (unsigned short*)alloc((size_t)N_NODES * 64 * sizeof(unsigned short));
    float* s_src    = (float*)alloc((size_t)N_NODES * sizeof(float));
    float* s_dst    = (float*)alloc((size_t)N_NODES * sizeof(float));
    int*   rowptr   = (int*)alloc((size_t)(N_NODES + 1) * sizeof(int));
    int*   colA     = (int*)alloc((size_t)ETOT * sizeof(int));
    int*   bcnt     = (int*)alloc((size_t)NB * sizeof(int));
    int*   pstart   = (int*)alloc((size_t)(NB + 1) * sizeof(int));
    int*   bnext    = (int*)alloc((size_t)NB * sizeof(int));
    float* pool_acc = (float*)alloc((size_t)(2 * N_GRAPHS) * sizeof(float));
    int2*  pairs    = (int2*)alloc((size_t)N_EDGES * sizeof(int2));  // dead after CSR build

    const int* e0 = edge;
    const int* e1 = edge + N_EDGES;

    // init + bucketed CSR build (by dst, self loops at slot 0 of each row)
    k_init<<<1, 256, 0, stream>>>(bcnt, pool_acc);
    k_bucket_hist<<<512, 256, 0, stream>>>(e1, bcnt);
    k_bucket_scan<<<1, 128, 0, stream>>>(bcnt, pstart, bnext);
    k_pair_scatter<<<PAIR_BLOCKS, 256, 0, stream>>>(e0, e1, bnext, pairs);
    k_csr_bucket<<<NB, 1024, 0, stream>>>(pairs, pstart, rowptr, colA);

    const int gemm_blocks = (N_NODES + 63) / 64;
    const float* hin = nullptr;
    for (int l = 0; l < 3; ++l) {
        k_gemm_score<<<gemm_blocks, 256, 0, stream>>>(
            hin, x, embed, Ws + (size_t)l * 4096, a_srcs + l * 64, a_dsts + l * 64,
            hWb, s_src, s_dst, (l == 0) ? 1 : 0);
        k_agg<<<(N_NODES + 3) / 4, 256, 0, stream>>>(
            hWb, colA, rowptr, s_src, s_dst, biases + l * 64, hbuf0,
            (l < 2) ? 0 : 1, batch, W_out, pool_acc);
        hin = hbuf0;
    }
    k_head<<<1, 256, 0, stream>>>(pool_acc, batch, b_out, out);
}

// Round 5
// 389.031 us; speedup vs baseline: 2.7225x; 2.7225x over previous
//
#include <hip/hip_runtime.h>
#include <hip/hip_bf16.h>
#include <float.h>

#define N_NODES 100000
#define N_EDGES 1600000
#define HIDDEN 64
#define N_GRAPHS 128
#define NEG_SLOPE 0.2f
#define ETOT (N_EDGES + N_NODES)

#define BSHIFT 10
#define NB ((N_NODES + 1023) >> BSHIFT)   // 98 buckets of 1024 nodes
#define PAIR_CHUNK 8192
#define PAIR_BLOCKS ((N_EDGES + PAIR_CHUNK - 1) / PAIR_CHUNK)  // 196

#define NREP 64           // pool accumulator replicas (atomic contention spreading)
#define REP_STRIDE 272    // 256 floats + 16 pad

__device__ __forceinline__ unsigned short f2bf(float f) {
    unsigned u = __float_as_uint(f);
    unsigned r = (u + 0x7FFFu + ((u >> 16) & 1u)) >> 16;  // RNE
    return (unsigned short)r;
}

// ---------------- init: zero bucket counters + pool accumulator replicas ----------------

__global__ void k_init(int* __restrict__ cnt, float* __restrict__ pool_acc) {
    int b = blockIdx.x, t = threadIdx.x;
    if (b == 0 && t < NB) cnt[t] = 0;
    if (t < 2 * N_GRAPHS) pool_acc[b * REP_STRIDE + t] = 0.f;
}

// ---------------- bucketed CSR build ----------------

__global__ __launch_bounds__(256) void k_bucket_hist(const int* __restrict__ dst,
                                                     int* __restrict__ bucket_cnt) {
    __shared__ int h[NB];
    int t = threadIdx.x;
    if (t < NB) h[t] = 0;
    __syncthreads();
    int stride = gridDim.x * blockDim.x;
    for (int e = blockIdx.x * blockDim.x + t; e < N_EDGES; e += stride)
        atomicAdd(&h[dst[e] >> BSHIFT], 1);
    __syncthreads();
    if (t < NB) atomicAdd(&bucket_cnt[t], h[t]);
}

__global__ void k_bucket_scan(const int* __restrict__ bucket_cnt,
                              int* __restrict__ pair_start,
                              int* __restrict__ bucket_next) {
    __shared__ int s[128];
    int t = threadIdx.x;
    int v = (t < NB) ? bucket_cnt[t] : 0;
    s[t] = v;
    __syncthreads();
    for (int off = 1; off < 128; off <<= 1) {
        int u = (t >= off) ? s[t - off] : 0;
        __syncthreads();
        s[t] += u;
        __syncthreads();
    }
    if (t < NB) {
        int ex = s[t] - v;
        pair_start[t] = ex;
        bucket_next[t] = ex;
    }
    if (t == 0) pair_start[NB] = N_EDGES;
}

__global__ __launch_bounds__(256) void k_pair_scatter(
    const int* __restrict__ e0, const int* __restrict__ e1,
    int* __restrict__ bucket_next, int2* __restrict__ pairs)
{
    __shared__ int cnt[NB];
    __shared__ int base[NB];
    int t = threadIdx.x;
    int ebase = blockIdx.x * PAIR_CHUNK;
    int ecount = min(PAIR_CHUNK, N_EDGES - ebase);

    if (t < NB) cnt[t] = 0;
    __syncthreads();
    for (int i = t; i < ecount; i += 256)
        atomicAdd(&cnt[e1[ebase + i] >> BSHIFT], 1);
    __syncthreads();
    if (t < NB) {
        base[t] = atomicAdd(&bucket_next[t], cnt[t]);
        cnt[t] = 0;
    }
    __syncthreads();
    for (int i = t; i < ecount; i += 256) {
        int s = e0[ebase + i];
        int d = e1[ebase + i];
        int b = d >> BSHIFT;
        int idx = atomicAdd(&cnt[b], 1);
        pairs[base[b] + idx] = make_int2(s, d);
    }
}

// One block per bucket: local degree histogram + wave-scan + col scatter in LDS.
// Self loop occupies slot 0 of each row.
__global__ __launch_bounds__(1024) void k_csr_bucket(
    const int2* __restrict__ pairs, const int* __restrict__ pair_start,
    int* __restrict__ rowptr, int* __restrict__ col)
{
    __shared__ int deg[1024];
    __shared__ int excl[1024];
    __shared__ int wsum[16];
    int b = blockIdx.x;
    int t = threadIdx.x;
    int nb = b << BSHIFT;
    int nodes = min(1024, N_NODES - nb);

    deg[t] = (t < nodes) ? 1 : 0;   // self loop
    __syncthreads();
    int p0 = pair_start[b], p1 = pair_start[b + 1];
    for (int i = p0 + t; i < p1; i += 1024)
        atomicAdd(&deg[pairs[i].y - nb], 1);
    __syncthreads();

    int val = deg[t];
    int x = val;
#pragma unroll
    for (int off = 1; off < 64; off <<= 1) {
        int y = __shfl_up(x, off);
        if ((t & 63) >= off) x += y;
    }
    if ((t & 63) == 63) wsum[t >> 6] = x;
    __syncthreads();
    if (t == 0) {
        int s = 0;
#pragma unroll
        for (int i = 0; i < 16; ++i) { int v = wsum[i]; wsum[i] = s; s += v; }
    }
    __syncthreads();
    int ex = x - val + wsum[t >> 6];  // exclusive prefix of local degrees
    excl[t] = ex;

    int colbase = p0 + nb;  // nb == #self-loops in preceding buckets
    if (t < nodes) {
        rowptr[nb + t] = colbase + ex;
        col[colbase + ex] = nb + t;  // self loop at slot 0
    }
    if (b == NB - 1 && t == 0) rowptr[N_NODES] = ETOT;

    deg[t] = 1;  // slot 0 taken by self loop
    __syncthreads();
    for (int i = p0 + t; i < p1; i += 1024) {
        int2 pr = pairs[i];
        int li = pr.y - nb;
        int pos = colbase + excl[li] + atomicAdd(&deg[li], 1);
        col[pos] = pr.x;
    }
}

// ---------------- per-layer GEMM + attention scores ----------------
// hWb (bf16) = h @ W ; s_src = hW @ a_s ; s_dst = hW @ a_d  (scores fp32)

__global__ __launch_bounds__(256) void k_gemm_score(
    const float* __restrict__ h, const int* __restrict__ x,
    const float* __restrict__ embed, const float* __restrict__ W,
    const float* __restrict__ a_s, const float* __restrict__ a_d,
    unsigned short* __restrict__ hWb, float* __restrict__ s_src,
    float* __restrict__ s_dst, int layer0)
{
    __shared__ float Wl[64 * 64];
    __shared__ float hT[64 * 68];  // [k][r], pitch 68
    int t = threadIdx.x;
    int r0 = blockIdx.x * 64;

    for (int i = t; i < 4096; i += 256) Wl[i] = W[i];
    for (int i = t; i < 4096; i += 256) {
        int r = i >> 6, k = i & 63;
        int row = r0 + r;
        float v = 0.f;
        if (row < N_NODES)
            v = layer0 ? embed[x[row] * 64 + k] : h[row * 64 + k];
        hT[k * 68 + r] = v;
    }
    __syncthreads();

    int tcol = t & 15;
    int trow = t >> 4;
    float acc[4][4];
#pragma unroll
    for (int i = 0; i < 4; ++i)
#pragma unroll
        for (int j = 0; j < 4; ++j) acc[i][j] = 0.f;

    for (int k = 0; k < 64; ++k) {
        float4 va = *(const float4*)&hT[k * 68 + trow * 4];
        float4 vb = *(const float4*)&Wl[k * 64 + tcol * 4];
        float a[4] = {va.x, va.y, va.z, va.w};
        float bb[4] = {vb.x, vb.y, vb.z, vb.w};
#pragma unroll
        for (int i = 0; i < 4; ++i)
#pragma unroll
            for (int j = 0; j < 4; ++j) acc[i][j] = fmaf(a[i], bb[j], acc[i][j]);
    }

    float4 as4 = *(const float4*)&a_s[tcol * 4];
    float4 ad4 = *(const float4*)&a_d[tcol * 4];
    float asr[4] = {as4.x, as4.y, as4.z, as4.w};
    float adr[4] = {ad4.x, ad4.y, ad4.z, ad4.w};

#pragma unroll
    for (int i = 0; i < 4; ++i) {
        int row = r0 + trow * 4 + i;
        float ps = 0.f, pd = 0.f;
#pragma unroll
        for (int j = 0; j < 4; ++j) {
            ps = fmaf(acc[i][j], asr[j], ps);
            pd = fmaf(acc[i][j], adr[j], pd);
        }
#pragma unroll
        for (int off = 8; off >= 1; off >>= 1) {
            ps += __shfl_xor(ps, off);
            pd += __shfl_xor(pd, off);
        }
        if (row < N_NODES) {
            ushort4 o;
            o.x = f2bf(acc[i][0]); o.y = f2bf(acc[i][1]);
            o.z = f2bf(acc[i][2]); o.w = f2bf(acc[i][3]);
            *(ushort4*)&hWb[row * 64 + tcol * 4] = o;
            if (tcol == 0) { s_src[row] = ps; s_dst[row] = pd; }
        }
    }
}

// ---------------- attention softmax + aggregation (one wave per dst node) ----------------
// mode 0: out = relu(agg + bias) -> hout
// mode 1 (last layer): project (agg + bias) @ W_out -> atomicAdd into pool_acc replica

__global__ __launch_bounds__(256) void k_agg(
    const unsigned short* __restrict__ hWb, const int* __restrict__ col,
    const int* __restrict__ rowptr, const float* __restrict__ s_src,
    const float* __restrict__ s_dst, const float* __restrict__ bias,
    float* __restrict__ hout, int mode,
    const int* __restrict__ batch, const float* __restrict__ W_out,
    float* __restrict__ pool_acc)
{
    __shared__ float2 stash[4][64];  // (alpha, elem-offset bits)
    int wave = threadIdx.x >> 6;
    int lane = threadIdx.x & 63;
    int node = blockIdx.x * 4 + wave;
    if (node >= N_NODES) return;

    int row = rowptr[node];
    int end = rowptr[node + 1];
    int deg = end - row;
    float sdi = s_dst[node];
    float* rep = pool_acc + (blockIdx.x & (NREP - 1)) * REP_STRIDE;

    if (deg <= 64) {
        int c = 0;
        float e = -FLT_MAX;
        if (lane < deg) {
            c = col[row + lane];
            float ee = s_src[c] + sdi;
            e = (ee >= 0.f) ? ee : NEG_SLOPE * ee;
        }
        float m = e;
#pragma unroll
        for (int off = 32; off >= 1; off >>= 1) m = fmaxf(m, __shfl_xor(m, off));
        float p = (lane < deg) ? __expf(e - m) : 0.f;
        float denom = p;
#pragma unroll
        for (int off = 32; off >= 1; off >>= 1) denom += __shfl_xor(denom, off);
        float inv = 1.f / denom;
        // lanes >= deg stash alpha=0, offset=0 (harmless reads of hWb[0..])
        stash[wave][lane] = make_float2(p * inv, __int_as_float(c * 64));

        int half = lane >> 5;   // which edge of the pair
        int hl = lane & 31;     // feature pair index: features 2*hl, 2*hl+1
        float acc0 = 0.f, acc1 = 0.f;
        int degr = (deg + 7) & ~7;
        for (int j = half; j < degr; j += 8) {
            float2 ac0 = stash[wave][j];
            float2 ac2 = stash[wave][j + 2];
            float2 ac4 = stash[wave][j + 4];
            float2 ac6 = stash[wave][j + 6];
            unsigned v0 = *(const unsigned*)&hWb[__float_as_int(ac0.y) + hl * 2];
            unsigned v2 = *(const unsigned*)&hWb[__float_as_int(ac2.y) + hl * 2];
            unsigned v4 = *(const unsigned*)&hWb[__float_as_int(ac4.y) + hl * 2];
            unsigned v6 = *(const unsigned*)&hWb[__float_as_int(ac6.y) + hl * 2];
            acc0 = fmaf(ac0.x, __uint_as_float(v0 << 16), acc0);
            acc1 = fmaf(ac0.x, __uint_as_float(v0 & 0xFFFF0000u), acc1);
            acc0 = fmaf(ac2.x, __uint_as_float(v2 << 16), acc0);
            acc1 = fmaf(ac2.x, __uint_as_float(v2 & 0xFFFF0000u), acc1);
            acc0 = fmaf(ac4.x, __uint_as_float(v4 << 16), acc0);
            acc1 = fmaf(ac4.x, __uint_as_float(v4 & 0xFFFF0000u), acc1);
            acc0 = fmaf(ac6.x, __uint_as_float(v6 << 16), acc0);
            acc1 = fmaf(ac6.x, __uint_as_float(v6 & 0xFFFF0000u), acc1);
        }
        acc0 += __shfl_xor(acc0, 32);
        acc1 += __shfl_xor(acc1, 32);
        if (half == 0) {
            float2 bb = ((const float2*)bias)[hl];
            float o0 = acc0 + bb.x, o1 = acc1 + bb.y;
            if (mode == 0) {
                o0 = fmaxf(o0, 0.f); o1 = fmaxf(o1, 0.f);
                *(float2*)&hout[node * 64 + hl * 2] = make_float2(o0, o1);
            } else {
                // project features (2*hl, 2*hl+1) onto W_out rows
                float4 w = *(const float4*)&W_out[4 * hl];
                float p0 = fmaf(o0, w.x, o1 * w.z);
                float p1 = fmaf(o0, w.y, o1 * w.w);
#pragma unroll
                for (int off = 16; off >= 1; off >>= 1) {
                    p0 += __shfl_xor(p0, off);
                    p1 += __shfl_xor(p1, off);
                }
                if (hl == 0) {
                    int g = batch[node];
                    atomicAdd(&rep[g * 2], p0);
                    atomicAdd(&rep[g * 2 + 1], p1);
                }
            }
        }
    } else {
        // generic path (deg > 64): statistically never hit
        float m = -FLT_MAX;
        for (int j = row + lane; j < end; j += 64) {
            float ee = s_src[col[j]] + sdi;
            ee = (ee >= 0.f) ? ee : NEG_SLOPE * ee;
            m = fmaxf(m, ee);
        }
#pragma unroll
        for (int off = 32; off >= 1; off >>= 1) m = fmaxf(m, __shfl_xor(m, off));
        float denom = 0.f;
        for (int j = row + lane; j < end; j += 64) {
            float ee = s_src[col[j]] + sdi;
            ee = (ee >= 0.f) ? ee : NEG_SLOPE * ee;
            denom += __expf(ee - m);
        }
#pragma unroll
        for (int off = 32; off >= 1; off >>= 1) denom += __shfl_xor(denom, off);
        float inv = 1.f / denom;
        float acc = 0.f;
        for (int j = row; j < end; ++j) {
            int cc = col[j];
            float ee = s_src[cc] + sdi;
            ee = (ee >= 0.f) ? ee : NEG_SLOPE * ee;
            unsigned hv = hWb[cc * 64 + lane];
            acc = fmaf(__expf(ee - m) * inv, __uint_as_float(hv << 16), acc);
        }
        float o = acc + bias[lane];
        if (mode == 0) {
            o = fmaxf(o, 0.f);
            hout[node * 64 + lane] = o;
        } else {
            float p0 = o * W_out[lane * 2];
            float p1 = o * W_out[lane * 2 + 1];
#pragma unroll
            for (int off = 32; off >= 1; off >>= 1) {
                p0 += __shfl_xor(p0, off);
                p1 += __shfl_xor(p1, off);
            }
            if (lane == 0) {
                int g = batch[node];
                atomicAdd(&rep[g * 2], p0);
                atomicAdd(&rep[g * 2 + 1], p1);
            }
        }
    }
}

// ---------------- head: reduce replicas, divide by count, add b_out ----------------

__device__ __forceinline__ int lower_bound_dev(const int* __restrict__ a, int n, int v) {
    int lo = 0, hi = n;
    while (lo < hi) {
        int mid = (lo + hi) >> 1;
        if (a[mid] < v) lo = mid + 1; else hi = mid;
    }
    return lo;
}

__global__ void k_head(const float* __restrict__ pool_acc,
                       const int* __restrict__ batch,
                       const float* __restrict__ b_out,
                       float* __restrict__ out)
{
    int t = threadIdx.x;
    if (t < 2 * N_GRAPHS) {
        float s = 0.f;
#pragma unroll 8
        for (int r = 0; r < NREP; ++r) s += pool_acc[r * REP_STRIDE + t];
        int g = t >> 1, c = t & 1;
        int start = lower_bound_dev(batch, N_NODES, g);
        int end = lower_bound_dev(batch, N_NODES, g + 1);
        float cnt = fmaxf((float)(end - start), 1.f);
        out[t] = s / cnt + b_out[c];
    }
}

// ---------------- launch ----------------

extern "C" void kernel_launch(void* const* d_in, const int* in_sizes, int n_in,
                              void* d_out, int out_size, void* d_ws, size_t ws_size,
                              hipStream_t stream) {
    const int*   x       = (const int*)d_in[0];
    const int*   edge    = (const int*)d_in[1];   // [2][E]
    const int*   batch   = (const int*)d_in[2];
    const float* embed   = (const float*)d_in[3];
    const float* Ws      = (const float*)d_in[4];
    const float* a_srcs  = (const float*)d_in[5];
    const float* a_dsts  = (const float*)d_in[6];
    const float* biases  = (const float*)d_in[7];
    const float* W_out   = (const float*)d_in[8];
    const float* b_out   = (const float*)d_in[9];
    float* out = (float*)d_out;

    char* ws = (char*)d_ws;
    size_t off = 0;
    auto alloc = [&](size_t bytes) -> void* {
        void* p = ws + off;
        off += (bytes + 255) & ~(size_t)255;
        return p;
    };
    float*          hbuf0  = (float*)alloc((size_t)N_NODES * 64 * sizeof(float));  // layer io fp32
    unsigned short* hWb    = (unsigned short*)alloc((size_t)N_NODES * 64 * sizeof(unsigned short));
    float* s_src    = (float*)alloc((size_t)N_NODES * sizeof(float));
    float* s_dst    = (float*)alloc((size_t)N_NODES * sizeof(float));
    int*   rowptr   = (int*)alloc((size_t)(N_NODES + 1) * sizeof(int));
    int*   colA     = (int*)alloc((size_t)ETOT * sizeof(int));
    int*   bcnt     = (int*)alloc((size_t)NB * sizeof(int));
    int*   pstart   = (int*)alloc((size_t)(NB + 1) * sizeof(int));
    int*   bnext    = (int*)alloc((size_t)NB * sizeof(int));
    float* pool_acc = (float*)alloc((size_t)(NREP * REP_STRIDE) * sizeof(float));
    int2*  pairs    = (int2*)alloc((size_t)N_EDGES * sizeof(int2));  // dead after CSR build

    const int* e0 = edge;
    const int* e1 = edge + N_EDGES;

    // init + bucketed CSR build (by dst, self loops at slot 0 of each row)
    k_init<<<NREP, 256, 0, stream>>>(bcnt, pool_acc);
    k_bucket_hist<<<512, 256, 0, stream>>>(e1, bcnt);
    k_bucket_scan<<<1, 128, 0, stream>>>(bcnt, pstart, bnext);
    k_pair_scatter<<<PAIR_BLOCKS, 256, 0, stream>>>(e0, e1, bnext, pairs);
    k_csr_bucket<<<NB, 1024, 0, stream>>>(pairs, pstart, rowptr, colA);

    const int gemm_blocks = (N_NODES + 63) / 64;
    const float* hin = nullptr;
    for (int l = 0; l < 3; ++l) {
        k_gemm_score<<<gemm_blocks, 256, 0, stream>>>(
            hin, x, embed, Ws + (size_t)l * 4096, a_srcs + l * 64, a_dsts + l * 64,
            hWb, s_src, s_dst, (l == 0) ? 1 : 0);
        k_agg<<<(N_NODES + 3) / 4, 256, 0, stream>>>(
            hWb, colA, rowptr, s_src, s_dst, biases + l * 64, hbuf0,
            (l < 2) ? 0 : 1, batch, W_out, pool_acc);
        hin = hbuf0;
    }
    k_head<<<1, 256, 0, stream>>>(pool_acc, batch, b_out, out);
}

// Round 6
// 380.296 us; speedup vs baseline: 2.7850x; 1.0230x over previous
//
#include <hip/hip_runtime.h>
#include <hip/hip_bf16.h>
#include <float.h>

#define N_NODES 100000
#define N_EDGES 1600000
#define HIDDEN 64
#define N_GRAPHS 128
#define NEG_SLOPE 0.2f
#define ETOT (N_EDGES + N_NODES)

#define BSHIFT 10
#define NB ((N_NODES + 1023) >> BSHIFT)   // 98 buckets of 1024 nodes
#define PAIR_CHUNK 4096
#define PAIR_BLOCKS ((N_EDGES + PAIR_CHUNK - 1) / PAIR_CHUNK)  // 391

#define NREP 64           // pool accumulator replicas (atomic contention spreading)
#define REP_STRIDE 272    // 256 floats + 16 pad

__device__ __forceinline__ unsigned short f2bf(float f) {
    unsigned u = __float_as_uint(f);
    unsigned r = (u + 0x7FFFu + ((u >> 16) & 1u)) >> 16;  // RNE
    return (unsigned short)r;
}

// ---------------- CSR build: per-chunk bucket counts (also zeroes pool_acc) ----------------

__global__ __launch_bounds__(256) void k_count(const int* __restrict__ e1,
                                               int* __restrict__ blockcnt,
                                               float* __restrict__ pool_acc) {
    __shared__ int h[NB];
    int t = threadIdx.x, b = blockIdx.x;
    if (t < NB) h[t] = 0;
    if (b < NREP && t < 2 * N_GRAPHS) pool_acc[b * REP_STRIDE + t] = 0.f;
    __syncthreads();
    int ebase = b * PAIR_CHUNK;
    int ecount = min(PAIR_CHUNK, N_EDGES - ebase);
    for (int i = t; i < ecount; i += 256)
        atomicAdd(&h[e1[ebase + i] >> BSHIFT], 1);
    __syncthreads();
    if (t < NB) blockcnt[b * NB + t] = h[t];
}

// one block: per-bucket serial scan over chunk counts -> per-block bases (in place),
// then bucket-total scan -> pair_start
__global__ void k_scan_counts(int* __restrict__ blockcnt, int* __restrict__ pair_start) {
    int t = threadIdx.x;
    int s = 0;
    if (t < NB) {
        for (int b = 0; b < PAIR_BLOCKS; ++b) {
            int v = blockcnt[b * NB + t];
            blockcnt[b * NB + t] = s;
            s += v;
        }
    }
    __shared__ int tot[128];
    tot[t] = (t < NB) ? s : 0;
    __syncthreads();
    for (int off = 1; off < 128; off <<= 1) {
        int u = (t >= off) ? tot[t - off] : 0;
        __syncthreads();
        tot[t] += u;
        __syncthreads();
    }
    if (t < NB) pair_start[t] = tot[t] - s;
    if (t == 0) pair_start[NB] = N_EDGES;
}

__global__ __launch_bounds__(256) void k_pair_scatter(
    const int* __restrict__ e0, const int* __restrict__ e1,
    const int* __restrict__ blockcnt, const int* __restrict__ pair_start,
    int* __restrict__ pairs)
{
    __shared__ int cnt[NB];
    __shared__ int base[NB];
    int t = threadIdx.x, b = blockIdx.x;
    if (t < NB) {
        cnt[t] = 0;
        base[t] = pair_start[t] + blockcnt[b * NB + t];
    }
    __syncthreads();
    int ebase = b * PAIR_CHUNK;
    int ecount = min(PAIR_CHUNK, N_EDGES - ebase);
    for (int i = t; i < ecount; i += 256) {
        int s = e0[ebase + i];
        int d = e1[ebase + i];
        int B = d >> BSHIFT;
        int idx = atomicAdd(&cnt[B], 1);
        pairs[base[B] + idx] = ((d & 1023) << 17) | s;   // 10b local dst | 17b src
    }
}

// One block per bucket: local degree histogram + wave-scan + col scatter in LDS.
// Self loop occupies slot 0 of each row.
__global__ __launch_bounds__(1024) void k_csr_bucket(
    const int* __restrict__ pairs, const int* __restrict__ pair_start,
    int* __restrict__ rowptr, int* __restrict__ col)
{
    __shared__ int deg[1024];
    __shared__ int excl[1024];
    __shared__ int wsum[16];
    int b = blockIdx.x;
    int t = threadIdx.x;
    int nb = b << BSHIFT;
    int nodes = min(1024, N_NODES - nb);

    deg[t] = (t < nodes) ? 1 : 0;   // self loop
    __syncthreads();
    int p0 = pair_start[b], p1 = pair_start[b + 1];
    for (int i = p0 + t; i < p1; i += 1024)
        atomicAdd(&deg[pairs[i] >> 17], 1);
    __syncthreads();

    int val = deg[t];
    int x = val;
#pragma unroll
    for (int off = 1; off < 64; off <<= 1) {
        int y = __shfl_up(x, off);
        if ((t & 63) >= off) x += y;
    }
    if ((t & 63) == 63) wsum[t >> 6] = x;
    __syncthreads();
    if (t == 0) {
        int s = 0;
#pragma unroll
        for (int i = 0; i < 16; ++i) { int v = wsum[i]; wsum[i] = s; s += v; }
    }
    __syncthreads();
    int ex = x - val + wsum[t >> 6];  // exclusive prefix of local degrees
    excl[t] = ex;

    int colbase = p0 + nb;  // nb == #self-loops in preceding buckets
    if (t < nodes) {
        rowptr[nb + t] = colbase + ex;
        col[colbase + ex] = nb + t;  // self loop at slot 0
    }
    if (b == NB - 1 && t == 0) rowptr[N_NODES] = ETOT;

    deg[t] = 1;  // slot 0 taken by self loop
    __syncthreads();
    for (int i = p0 + t; i < p1; i += 1024) {
        int p = pairs[i];
        int li = p >> 17;
        int pos = colbase + excl[li] + atomicAdd(&deg[li], 1);
        col[pos] = p & 0x1FFFF;
    }
}

// ---------------- per-layer GEMM + attention scores ----------------
// hWb (bf16) = h @ W ; s_src = hW @ a_s ; s_dst = hW @ a_d  (scores fp32)

__global__ __launch_bounds__(256) void k_gemm_score(
    const float* __restrict__ h, const int* __restrict__ x,
    const float* __restrict__ embed, const float* __restrict__ W,
    const float* __restrict__ a_s, const float* __restrict__ a_d,
    unsigned short* __restrict__ hWb, float* __restrict__ s_src,
    float* __restrict__ s_dst, int layer0)
{
    __shared__ float Wl[64 * 64];
    __shared__ float hT[64 * 68];  // [k][r], pitch 68
    int t = threadIdx.x;
    int r0 = blockIdx.x * 64;

    for (int i = t; i < 4096; i += 256) Wl[i] = W[i];
    for (int i = t; i < 4096; i += 256) {
        int r = i >> 6, k = i & 63;
        int row = r0 + r;
        float v = 0.f;
        if (row < N_NODES)
            v = layer0 ? embed[x[row] * 64 + k] : h[row * 64 + k];
        hT[k * 68 + r] = v;
    }
    __syncthreads();

    int tcol = t & 15;
    int trow = t >> 4;
    float acc[4][4];
#pragma unroll
    for (int i = 0; i < 4; ++i)
#pragma unroll
        for (int j = 0; j < 4; ++j) acc[i][j] = 0.f;

    for (int k = 0; k < 64; ++k) {
        float4 va = *(const float4*)&hT[k * 68 + trow * 4];
        float4 vb = *(const float4*)&Wl[k * 64 + tcol * 4];
        float a[4] = {va.x, va.y, va.z, va.w};
        float bb[4] = {vb.x, vb.y, vb.z, vb.w};
#pragma unroll
        for (int i = 0; i < 4; ++i)
#pragma unroll
            for (int j = 0; j < 4; ++j) acc[i][j] = fmaf(a[i], bb[j], acc[i][j]);
    }

    float4 as4 = *(const float4*)&a_s[tcol * 4];
    float4 ad4 = *(const float4*)&a_d[tcol * 4];
    float asr[4] = {as4.x, as4.y, as4.z, as4.w};
    float adr[4] = {ad4.x, ad4.y, ad4.z, ad4.w};

#pragma unroll
    for (int i = 0; i < 4; ++i) {
        int row = r0 + trow * 4 + i;
        float ps = 0.f, pd = 0.f;
#pragma unroll
        for (int j = 0; j < 4; ++j) {
            ps = fmaf(acc[i][j], asr[j], ps);
            pd = fmaf(acc[i][j], adr[j], pd);
        }
#pragma unroll
        for (int off = 8; off >= 1; off >>= 1) {
            ps += __shfl_xor(ps, off);
            pd += __shfl_xor(pd, off);
        }
        if (row < N_NODES) {
            ushort4 o;
            o.x = f2bf(acc[i][0]); o.y = f2bf(acc[i][1]);
            o.z = f2bf(acc[i][2]); o.w = f2bf(acc[i][3]);
            *(ushort4*)&hWb[row * 64 + tcol * 4] = o;
            if (tcol == 0) { s_src[row] = ps; s_dst[row] = pd; }
        }
    }
}

// ---------------- attention softmax + aggregation (one wave per dst node) ----------------
// Quarter-wave per edge: 16 lanes x dwordx2 = 128 B row; 16 edges per 4-load iter.
// mode 0: out = relu(agg + bias) -> hout
// mode 1 (last layer): project (agg + bias) @ W_out -> atomicAdd into pool_acc replica

__global__ __launch_bounds__(256) void k_agg(
    const unsigned short* __restrict__ hWb, const int* __restrict__ col,
    const int* __restrict__ rowptr, const float* __restrict__ s_src,
    const float* __restrict__ s_dst, const float* __restrict__ bias,
    float* __restrict__ hout, int mode,
    const int* __restrict__ batch, const float* __restrict__ W_out,
    float* __restrict__ pool_acc)
{
    __shared__ float2 stash[4][64];  // (alpha, row byte-offset bits)
    int wave = threadIdx.x >> 6;
    int lane = threadIdx.x & 63;
    int node = blockIdx.x * 4 + wave;
    if (node >= N_NODES) return;

    int row = rowptr[node];
    int end = rowptr[node + 1];
    int deg = end - row;
    float sdi = s_dst[node];
    float* rep = pool_acc + (blockIdx.x & (NREP - 1)) * REP_STRIDE;
    const char* hb = (const char*)hWb;

    if (deg <= 64) {
        int c = 0;
        float p = 0.f;
        if (lane < deg) {
            c = col[row + lane];
            float ee = s_src[c] + sdi;
            ee = (ee >= 0.f) ? ee : NEG_SLOPE * ee;
            p = __expf(ee);   // no max-sub: |e| small, fp32-safe
        }
        float denom = p;
#pragma unroll
        for (int off = 32; off >= 1; off >>= 1) denom += __shfl_xor(denom, off);
        float inv = 1.f / denom;
        // lanes >= deg stash alpha=0, offset=0 (harmless hot reads of hWb[0..])
        stash[wave][lane] = make_float2(p * inv, __int_as_float(c * 128));

        int q = lane >> 4;       // quarter: which edge of the group of 4
        int f = lane & 15;       // feature group: features 4f..4f+3
        int f8 = f * 8;          // byte offset within row
        float acc0 = 0.f, acc1 = 0.f, acc2 = 0.f, acc3 = 0.f;
        int degr = (deg + 15) & ~15;
        for (int j = q; j < degr; j += 16) {
            float2 a0 = stash[wave][j];
            float2 a1 = stash[wave][j + 4];
            float2 a2 = stash[wave][j + 8];
            float2 a3 = stash[wave][j + 12];
            uint2 v0 = *(const uint2*)(hb + (__float_as_int(a0.y) + f8));
            uint2 v1 = *(const uint2*)(hb + (__float_as_int(a1.y) + f8));
            uint2 v2 = *(const uint2*)(hb + (__float_as_int(a2.y) + f8));
            uint2 v3 = *(const uint2*)(hb + (__float_as_int(a3.y) + f8));
            acc0 = fmaf(a0.x, __uint_as_float(v0.x << 16), acc0);
            acc1 = fmaf(a0.x, __uint_as_float(v0.x & 0xFFFF0000u), acc1);
            acc2 = fmaf(a0.x, __uint_as_float(v0.y << 16), acc2);
            acc3 = fmaf(a0.x, __uint_as_float(v0.y & 0xFFFF0000u), acc3);
            acc0 = fmaf(a1.x, __uint_as_float(v1.x << 16), acc0);
            acc1 = fmaf(a1.x, __uint_as_float(v1.x & 0xFFFF0000u), acc1);
            acc2 = fmaf(a1.x, __uint_as_float(v1.y << 16), acc2);
            acc3 = fmaf(a1.x, __uint_as_float(v1.y & 0xFFFF0000u), acc3);
            acc0 = fmaf(a2.x, __uint_as_float(v2.x << 16), acc0);
            acc1 = fmaf(a2.x, __uint_as_float(v2.x & 0xFFFF0000u), acc1);
            acc2 = fmaf(a2.x, __uint_as_float(v2.y << 16), acc2);
            acc3 = fmaf(a2.x, __uint_as_float(v2.y & 0xFFFF0000u), acc3);
            acc0 = fmaf(a3.x, __uint_as_float(v3.x << 16), acc0);
            acc1 = fmaf(a3.x, __uint_as_float(v3.x & 0xFFFF0000u), acc1);
            acc2 = fmaf(a3.x, __uint_as_float(v3.y << 16), acc2);
            acc3 = fmaf(a3.x, __uint_as_float(v3.y & 0xFFFF0000u), acc3);
        }
        acc0 += __shfl_xor(acc0, 16); acc0 += __shfl_xor(acc0, 32);
        acc1 += __shfl_xor(acc1, 16); acc1 += __shfl_xor(acc1, 32);
        acc2 += __shfl_xor(acc2, 16); acc2 += __shfl_xor(acc2, 32);
        acc3 += __shfl_xor(acc3, 16); acc3 += __shfl_xor(acc3, 32);

        if (lane < 16) {
            float4 bb = *(const float4*)&bias[4 * f];
            float o0 = acc0 + bb.x, o1 = acc1 + bb.y;
            float o2 = acc2 + bb.z, o3 = acc3 + bb.w;
            if (mode == 0) {
                o0 = fmaxf(o0, 0.f); o1 = fmaxf(o1, 0.f);
                o2 = fmaxf(o2, 0.f); o3 = fmaxf(o3, 0.f);
                *(float4*)&hout[node * 64 + 4 * f] = make_float4(o0, o1, o2, o3);
            } else {
                float4 wa = *(const float4*)&W_out[8 * f];      // rows 4f, 4f+1
                float4 wb = *(const float4*)&W_out[8 * f + 4];  // rows 4f+2, 4f+3
                float p0 = o0 * wa.x + o1 * wa.z + o2 * wb.x + o3 * wb.z;
                float p1 = o0 * wa.y + o1 * wa.w + o2 * wb.y + o3 * wb.w;
#pragma unroll
                for (int off = 8; off >= 1; off >>= 1) {
                    p0 += __shfl_xor(p0, off);
                    p1 += __shfl_xor(p1, off);
                }
                if (f == 0) {
                    int g = batch[node];
                    atomicAdd(&rep[g * 2], p0);
                    atomicAdd(&rep[g * 2 + 1], p1);
                }
            }
        }
    } else {
        // generic path (deg > 64): statistically never hit
        float m = -FLT_MAX;
        for (int j = row + lane; j < end; j += 64) {
            float ee = s_src[col[j]] + sdi;
            ee = (ee >= 0.f) ? ee : NEG_SLOPE * ee;
            m = fmaxf(m, ee);
        }
#pragma unroll
        for (int off = 32; off >= 1; off >>= 1) m = fmaxf(m, __shfl_xor(m, off));
        float denom = 0.f;
        for (int j = row + lane; j < end; j += 64) {
            float ee = s_src[col[j]] + sdi;
            ee = (ee >= 0.f) ? ee : NEG_SLOPE * ee;
            denom += __expf(ee - m);
        }
#pragma unroll
        for (int off = 32; off >= 1; off >>= 1) denom += __shfl_xor(denom, off);
        float inv = 1.f / denom;
        float acc = 0.f;
        for (int j = row; j < end; ++j) {
            int cc = col[j];
            float ee = s_src[cc] + sdi;
            ee = (ee >= 0.f) ? ee : NEG_SLOPE * ee;
            unsigned hv = hWb[cc * 64 + lane];
            acc = fmaf(__expf(ee - m) * inv, __uint_as_float(hv << 16), acc);
        }
        float o = acc + bias[lane];
        if (mode == 0) {
            o = fmaxf(o, 0.f);
            hout[node * 64 + lane] = o;
        } else {
            float p0 = o * W_out[lane * 2];
            float p1 = o * W_out[lane * 2 + 1];
#pragma unroll
            for (int off = 32; off >= 1; off >>= 1) {
                p0 += __shfl_xor(p0, off);
                p1 += __shfl_xor(p1, off);
            }
            if (lane == 0) {
                int g = batch[node];
                atomicAdd(&rep[g * 2], p0);
                atomicAdd(&rep[g * 2 + 1], p1);
            }
        }
    }
}

// ---------------- head: reduce replicas, divide by count, add b_out ----------------

__device__ __forceinline__ int lower_bound_dev(const int* __restrict__ a, int n, int v) {
    int lo = 0, hi = n;
    while (lo < hi) {
        int mid = (lo + hi) >> 1;
        if (a[mid] < v) lo = mid + 1; else hi = mid;
    }
    return lo;
}

__global__ void k_head(const float* __restrict__ pool_acc,
                       const int* __restrict__ batch,
                       const float* __restrict__ b_out,
                       float* __restrict__ out)
{
    int t = threadIdx.x;
    if (t < 2 * N_GRAPHS) {
        float s = 0.f;
#pragma unroll 8
        for (int r = 0; r < NREP; ++r) s += pool_acc[r * REP_STRIDE + t];
        int g = t >> 1, c = t & 1;
        int start = lower_bound_dev(batch, N_NODES, g);
        int end = lower_bound_dev(batch, N_NODES, g + 1);
        float cnt = fmaxf((float)(end - start), 1.f);
        out[t] = s / cnt + b_out[c];
    }
}

// ---------------- launch ----------------

extern "C" void kernel_launch(void* const* d_in, const int* in_sizes, int n_in,
                              void* d_out, int out_size, void* d_ws, size_t ws_size,
                              hipStream_t stream) {
    const int*   x       = (const int*)d_in[0];
    const int*   edge    = (const int*)d_in[1];   // [2][E]
    const int*   batch   = (const int*)d_in[2];
    const float* embed   = (const float*)d_in[3];
    const float* Ws      = (const float*)d_in[4];
    const float* a_srcs  = (const float*)d_in[5];
    const float* a_dsts  = (const float*)d_in[6];
    const float* biases  = (const float*)d_in[7];
    const float* W_out   = (const float*)d_in[8];
    const float* b_out   = (const float*)d_in[9];
    float* out = (float*)d_out;

    char* ws = (char*)d_ws;
    size_t off = 0;
    auto alloc = [&](size_t bytes) -> void* {
        void* p = ws + off;
        off += (bytes + 255) & ~(size_t)255;
        return p;
    };
    float*          hbuf0  = (float*)alloc((size_t)N_NODES * 64 * sizeof(float));  // layer io fp32
    unsigned short* hWb    = (unsigned short*)alloc((size_t)N_NODES * 64 * sizeof(unsigned short));
    float* s_src    = (float*)alloc((size_t)N_NODES * sizeof(float));
    float* s_dst    = (float*)alloc((size_t)N_NODES * sizeof(float));
    int*   rowptr   = (int*)alloc((size_t)(N_NODES + 1) * sizeof(int));
    int*   colA     = (int*)alloc((size_t)ETOT * sizeof(int));
    int*   blockcnt = (int*)alloc((size_t)PAIR_BLOCKS * NB * sizeof(int));
    int*   pstart   = (int*)alloc((size_t)(NB + 1) * sizeof(int));
    float* pool_acc = (float*)alloc((size_t)(NREP * REP_STRIDE) * sizeof(float));
    int*   pairs    = (int*)alloc((size_t)N_EDGES * sizeof(int));  // dead after CSR build

    const int* e0 = edge;
    const int* e1 = edge + N_EDGES;

    // bucketed CSR build (by dst, self loops at slot 0 of each row)
    k_count<<<PAIR_BLOCKS, 256, 0, stream>>>(e1, blockcnt, pool_acc);
    k_scan_counts<<<1, 128, 0, stream>>>(blockcnt, pstart);
    k_pair_scatter<<<PAIR_BLOCKS, 256, 0, stream>>>(e0, e1, blockcnt, pstart, pairs);
    k_csr_bucket<<<NB, 1024, 0, stream>>>(pairs, pstart, rowptr, colA);

    const int gemm_blocks = (N_NODES + 63) / 64;
    const float* hin = nullptr;
    for (int l = 0; l < 3; ++l) {
        k_gemm_score<<<gemm_blocks, 256, 0, stream>>>(
            hin, x, embed, Ws + (size_t)l * 4096, a_srcs + l * 64, a_dsts + l * 64,
            hWb, s_src, s_dst, (l == 0) ? 1 : 0);
        k_agg<<<(N_NODES + 3) / 4, 256, 0, stream>>>(
            hWb, colA, rowptr, s_src, s_dst, biases + l * 64, hbuf0,
            (l < 2) ? 0 : 1, batch, W_out, pool_acc);
        hin = hbuf0;
    }
    k_head<<<1, 256, 0, stream>>>(pool_acc, batch, b_out, out);
}

// Round 7
// 371.036 us; speedup vs baseline: 2.8545x; 1.0250x over previous
//
#include <hip/hip_runtime.h>
#include <hip/hip_bf16.h>
#include <float.h>

#define N_NODES 100000
#define N_EDGES 1600000
#define HIDDEN 64
#define N_GRAPHS 128
#define NEG_SLOPE 0.2f
#define ETOT (N_EDGES + N_NODES)

#define BSHIFT 10
#define NB ((N_NODES + 1023) >> BSHIFT)   // 98 buckets of 1024 nodes
#define PAIR_CHUNK 4096
#define PAIR_BLOCKS ((N_EDGES + PAIR_CHUNK - 1) / PAIR_CHUNK)  // 391

#define NREP 64           // pool accumulator replicas (atomic contention spreading)
#define REP_STRIDE 272    // 256 floats + 16 pad

__device__ __forceinline__ unsigned short f2bf(float f) {
    unsigned u = __float_as_uint(f);
    unsigned r = (u + 0x7FFFu + ((u >> 16) & 1u)) >> 16;  // RNE
    return (unsigned short)r;
}
__device__ __forceinline__ float blo(unsigned u) { return __uint_as_float(u << 16); }
__device__ __forceinline__ float bhi(unsigned u) { return __uint_as_float(u & 0xFFFF0000u); }

// ---------------- CSR build: per-chunk bucket counts (also zeroes pool_acc) ----------------

__global__ __launch_bounds__(256) void k_count(const int* __restrict__ e1,
                                               int* __restrict__ blockcnt,
                                               float* __restrict__ pool_acc) {
    __shared__ int h[NB];
    int t = threadIdx.x, b = blockIdx.x;
    if (t < NB) h[t] = 0;
    if (b < NREP && t < 2 * N_GRAPHS) pool_acc[b * REP_STRIDE + t] = 0.f;
    __syncthreads();
    int ebase = b * PAIR_CHUNK;
    int ecount = min(PAIR_CHUNK, N_EDGES - ebase);
    for (int i = t; i < ecount; i += 256)
        atomicAdd(&h[e1[ebase + i] >> BSHIFT], 1);
    __syncthreads();
    if (t < NB) blockcnt[b * NB + t] = h[t];
}

// one wave per bucket: exclusive scan over its 391 chunk counts (in place) + total
__global__ __launch_bounds__(64) void k_scan_bases(int* __restrict__ blockcnt,
                                                   int* __restrict__ btot) {
    int b = blockIdx.x;
    int lane = threadIdx.x;
    int s = 0;
    for (int base = 0; base < PAIR_BLOCKS; base += 64) {
        int c = base + lane;
        int v = (c < PAIR_BLOCKS) ? blockcnt[c * NB + b] : 0;
        int xv = v;
#pragma unroll
        for (int off = 1; off < 64; off <<= 1) {
            int y = __shfl_up(xv, off);
            if (lane >= off) xv += y;
        }
        if (c < PAIR_BLOCKS) blockcnt[c * NB + b] = s + xv - v;
        s += __shfl(xv, 63);
    }
    if (lane == 0) btot[b] = s;
}

__global__ void k_scan_buckets(const int* __restrict__ btot, int* __restrict__ pair_start) {
    __shared__ int tot[128];
    int t = threadIdx.x;
    int v = (t < NB) ? btot[t] : 0;
    tot[t] = v;
    __syncthreads();
    for (int off = 1; off < 128; off <<= 1) {
        int u = (t >= off) ? tot[t - off] : 0;
        __syncthreads();
        tot[t] += u;
        __syncthreads();
    }
    if (t < NB) pair_start[t] = tot[t] - v;
    if (t == 0) pair_start[NB] = N_EDGES;
}

__global__ __launch_bounds__(256) void k_pair_scatter(
    const int* __restrict__ e0, const int* __restrict__ e1,
    const int* __restrict__ blockcnt, const int* __restrict__ pair_start,
    int* __restrict__ pairs)
{
    __shared__ int cnt[NB];
    __shared__ int base[NB];
    int t = threadIdx.x, b = blockIdx.x;
    if (t < NB) {
        cnt[t] = 0;
        base[t] = pair_start[t] + blockcnt[b * NB + t];
    }
    __syncthreads();
    int ebase = b * PAIR_CHUNK;
    int ecount = min(PAIR_CHUNK, N_EDGES - ebase);
    for (int i = t; i < ecount; i += 256) {
        int s = e0[ebase + i];
        int d = e1[ebase + i];
        int B = d >> BSHIFT;
        int idx = atomicAdd(&cnt[B], 1);
        pairs[base[B] + idx] = ((d & 1023) << 17) | s;   // 10b local dst | 17b src
    }
}

// One block per bucket: local degree histogram + wave-scan + col scatter in LDS.
// Self loop occupies slot 0 of each row.
__global__ __launch_bounds__(1024) void k_csr_bucket(
    const int* __restrict__ pairs, const int* __restrict__ pair_start,
    int* __restrict__ rowptr, int* __restrict__ col)
{
    __shared__ int deg[1024];
    __shared__ int excl[1024];
    __shared__ int wsum[16];
    int b = blockIdx.x;
    int t = threadIdx.x;
    int nb = b << BSHIFT;
    int nodes = min(1024, N_NODES - nb);

    deg[t] = (t < nodes) ? 1 : 0;   // self loop
    __syncthreads();
    int p0 = pair_start[b], p1 = pair_start[b + 1];
    for (int i = p0 + t; i < p1; i += 1024)
        atomicAdd(&deg[pairs[i] >> 17], 1);
    __syncthreads();

    int val = deg[t];
    int x = val;
#pragma unroll
    for (int off = 1; off < 64; off <<= 1) {
        int y = __shfl_up(x, off);
        if ((t & 63) >= off) x += y;
    }
    if ((t & 63) == 63) wsum[t >> 6] = x;
    __syncthreads();
    if (t == 0) {
        int s = 0;
#pragma unroll
        for (int i = 0; i < 16; ++i) { int v = wsum[i]; wsum[i] = s; s += v; }
    }
    __syncthreads();
    int ex = x - val + wsum[t >> 6];  // exclusive prefix of local degrees
    excl[t] = ex;

    int colbase = p0 + nb;  // nb == #self-loops in preceding buckets
    if (t < nodes) {
        rowptr[nb + t] = colbase + ex;
        col[colbase + ex] = nb + t;  // self loop at slot 0
    }
    if (b == NB - 1 && t == 0) rowptr[N_NODES] = ETOT;

    deg[t] = 1;  // slot 0 taken by self loop
    __syncthreads();
    for (int i = p0 + t; i < p1; i += 1024) {
        int p = pairs[i];
        int li = p >> 17;
        int pos = colbase + excl[li] + atomicAdd(&deg[li], 1);
        col[pos] = p & 0x1FFFF;
    }
}

// ---------------- per-layer GEMM + attention scores ----------------
// hWb (bf16) = h @ W ; s_src = hW @ a_s ; s_dst = hW @ a_d  (scores fp32)
// h input: fp32 embed gather (layer 0) or bf16 activations (layers 1,2)

__global__ __launch_bounds__(256) void k_gemm_score(
    const void* __restrict__ hvoid, const int* __restrict__ x,
    const float* __restrict__ embed, const float* __restrict__ W,
    const float* __restrict__ a_s, const float* __restrict__ a_d,
    unsigned short* __restrict__ hWb, float* __restrict__ s_src,
    float* __restrict__ s_dst, int layer0)
{
    __shared__ float Wl[64 * 64];
    __shared__ float hT[64 * 68];  // [k][r], pitch 68
    int t = threadIdx.x;
    int r0 = blockIdx.x * 64;

    for (int i = t; i < 4096; i += 256) Wl[i] = W[i];
    if (layer0) {
        for (int i = t; i < 4096; i += 256) {
            int r = i >> 6, k = i & 63;
            int row = r0 + r;
            float v = (row < N_NODES) ? embed[x[row] * 64 + k] : 0.f;
            hT[k * 68 + r] = v;
        }
    } else {
        const unsigned* h32 = (const unsigned*)hvoid;
        for (int i = t; i < 2048; i += 256) {
            int r = i >> 5, m = i & 31;   // features 2m, 2m+1
            int row = r0 + r;
            unsigned u = (row < N_NODES) ? h32[row * 32 + m] : 0u;
            hT[(2 * m) * 68 + r]     = blo(u);
            hT[(2 * m + 1) * 68 + r] = bhi(u);
        }
    }
    __syncthreads();

    int tcol = t & 15;
    int trow = t >> 4;
    float acc[4][4];
#pragma unroll
    for (int i = 0; i < 4; ++i)
#pragma unroll
        for (int j = 0; j < 4; ++j) acc[i][j] = 0.f;

    for (int k = 0; k < 64; ++k) {
        float4 va = *(const float4*)&hT[k * 68 + trow * 4];
        float4 vb = *(const float4*)&Wl[k * 64 + tcol * 4];
        float a[4] = {va.x, va.y, va.z, va.w};
        float bb[4] = {vb.x, vb.y, vb.z, vb.w};
#pragma unroll
        for (int i = 0; i < 4; ++i)
#pragma unroll
            for (int j = 0; j < 4; ++j) acc[i][j] = fmaf(a[i], bb[j], acc[i][j]);
    }

    float4 as4 = *(const float4*)&a_s[tcol * 4];
    float4 ad4 = *(const float4*)&a_d[tcol * 4];
    float asr[4] = {as4.x, as4.y, as4.z, as4.w};
    float adr[4] = {ad4.x, ad4.y, ad4.z, ad4.w};

#pragma unroll
    for (int i = 0; i < 4; ++i) {
        int row = r0 + trow * 4 + i;
        float ps = 0.f, pd = 0.f;
#pragma unroll
        for (int j = 0; j < 4; ++j) {
            ps = fmaf(acc[i][j], asr[j], ps);
            pd = fmaf(acc[i][j], adr[j], pd);
        }
#pragma unroll
        for (int off = 8; off >= 1; off >>= 1) {
            ps += __shfl_xor(ps, off);
            pd += __shfl_xor(pd, off);
        }
        if (row < N_NODES) {
            ushort4 o;
            o.x = f2bf(acc[i][0]); o.y = f2bf(acc[i][1]);
            o.z = f2bf(acc[i][2]); o.w = f2bf(acc[i][3]);
            *(ushort4*)&hWb[row * 64 + tcol * 4] = o;
            if (tcol == 0) { s_src[row] = ps; s_dst[row] = pd; }
        }
    }
}

// ---------------- attention softmax + aggregation (one wave per dst node) ----------------
// 8 lanes per edge: uint4 = full 128-B bf16 row; 8 edges per load instruction.
// Softmax stashes UNNORMALIZED p; 1/denom applied in epilogue (reduction overlaps loads).
// mode 0: hout(bf16) = relu(agg + bias)
// mode 1 (last layer): project (agg + bias) @ W_out -> atomicAdd into pool_acc replica

__global__ __launch_bounds__(256) void k_agg(
    const unsigned short* __restrict__ hWb, const int* __restrict__ col,
    const int* __restrict__ rowptr, const float* __restrict__ s_src,
    const float* __restrict__ s_dst, const float* __restrict__ bias,
    unsigned short* __restrict__ hout, int mode,
    const int* __restrict__ batch, const float* __restrict__ W_out,
    float* __restrict__ pool_acc)
{
    __shared__ float2 stash[4][64];  // (p, row byte-offset bits)
    int wave = threadIdx.x >> 6;
    int lane = threadIdx.x & 63;
    int node = blockIdx.x * 4 + wave;
    if (node >= N_NODES) return;

    int row = rowptr[node];
    int end = rowptr[node + 1];
    int deg = end - row;
    float sdi = s_dst[node];
    float* rep = pool_acc + (blockIdx.x & (NREP - 1)) * REP_STRIDE;
    const char* hb = (const char*)hWb;

    if (deg <= 64) {
        int c = 0;
        float p = 0.f;
        if (lane < deg) {
            c = col[row + lane];
            float ee = s_src[c] + sdi;
            ee = (ee >= 0.f) ? ee : NEG_SLOPE * ee;
            p = __expf(ee);   // no max-sub: |e| small, fp32-safe
        }
        // lanes >= deg stash p=0, offset=0 (harmless L1-hot reads of hWb row 0)
        stash[wave][lane] = make_float2(p, __int_as_float(c * 128));

        int e8 = lane >> 3;      // edge slot within group of 8
        int fo = (lane & 7) * 16; // byte offset of this lane's feature octet
        float acc[8];
#pragma unroll
        for (int i = 0; i < 8; ++i) acc[i] = 0.f;
        int degr = (deg + 7) & ~7;
        for (int j = e8; j < degr; j += 8) {
            float2 ap = stash[wave][j];
            uint4 v = *(const uint4*)(hb + (__float_as_int(ap.y) + fo));
            float w = ap.x;
            acc[0] = fmaf(w, blo(v.x), acc[0]);
            acc[1] = fmaf(w, bhi(v.x), acc[1]);
            acc[2] = fmaf(w, blo(v.y), acc[2]);
            acc[3] = fmaf(w, bhi(v.y), acc[3]);
            acc[4] = fmaf(w, blo(v.z), acc[4]);
            acc[5] = fmaf(w, bhi(v.z), acc[5]);
            acc[6] = fmaf(w, blo(v.w), acc[6]);
            acc[7] = fmaf(w, bhi(v.w), acc[7]);
        }
        // denominator reduction (overlaps with in-flight gather loads)
        float denom = p;
#pragma unroll
        for (int off = 32; off >= 1; off >>= 1) denom += __shfl_xor(denom, off);
        float inv = 1.f / denom;
        // reduce edge-slot partials: lanes {l, l+8, ..., l+56} hold same feature octet
#pragma unroll
        for (int i = 0; i < 8; ++i) {
            acc[i] += __shfl_xor(acc[i], 8);
            acc[i] += __shfl_xor(acc[i], 16);
            acc[i] += __shfl_xor(acc[i], 32);
        }
        float p0 = 0.f, p1 = 0.f;
        if (lane < 8) {
            float4 b0 = *(const float4*)&bias[8 * lane];
            float4 b1 = *(const float4*)&bias[8 * lane + 4];
            float o0 = fmaf(acc[0], inv, b0.x), o1 = fmaf(acc[1], inv, b0.y);
            float o2 = fmaf(acc[2], inv, b0.z), o3 = fmaf(acc[3], inv, b0.w);
            float o4 = fmaf(acc[4], inv, b1.x), o5 = fmaf(acc[5], inv, b1.y);
            float o6 = fmaf(acc[6], inv, b1.z), o7 = fmaf(acc[7], inv, b1.w);
            if (mode == 0) {
                uint4 pk;
                pk.x = (unsigned)f2bf(fmaxf(o0, 0.f)) | ((unsigned)f2bf(fmaxf(o1, 0.f)) << 16);
                pk.y = (unsigned)f2bf(fmaxf(o2, 0.f)) | ((unsigned)f2bf(fmaxf(o3, 0.f)) << 16);
                pk.z = (unsigned)f2bf(fmaxf(o4, 0.f)) | ((unsigned)f2bf(fmaxf(o5, 0.f)) << 16);
                pk.w = (unsigned)f2bf(fmaxf(o6, 0.f)) | ((unsigned)f2bf(fmaxf(o7, 0.f)) << 16);
                *(uint4*)&hout[node * 64 + lane * 8] = pk;
            } else {
                float4 w0 = *(const float4*)&W_out[16 * lane];
                float4 w1 = *(const float4*)&W_out[16 * lane + 4];
                float4 w2 = *(const float4*)&W_out[16 * lane + 8];
                float4 w3 = *(const float4*)&W_out[16 * lane + 12];
                p0 = o0 * w0.x + o1 * w0.z + o2 * w1.x + o3 * w1.z
                   + o4 * w2.x + o5 * w2.z + o6 * w3.x + o7 * w3.z;
                p1 = o0 * w0.y + o1 * w0.w + o2 * w1.y + o3 * w1.w
                   + o4 * w2.y + o5 * w2.w + o6 * w3.y + o7 * w3.w;
            }
        }
        if (mode != 0) {
#pragma unroll
            for (int off = 4; off >= 1; off >>= 1) {
                p0 += __shfl_xor(p0, off);
                p1 += __shfl_xor(p1, off);
            }
            if (lane == 0) {
                int g = batch[node];
                atomicAdd(&rep[g * 2], p0);
                atomicAdd(&rep[g * 2 + 1], p1);
            }
        }
    } else {
        // generic path (deg > 64): statistically never hit
        float m = -FLT_MAX;
        for (int j = row + lane; j < end; j += 64) {
            float ee = s_src[col[j]] + sdi;
            ee = (ee >= 0.f) ? ee : NEG_SLOPE * ee;
            m = fmaxf(m, ee);
        }
#pragma unroll
        for (int off = 32; off >= 1; off >>= 1) m = fmaxf(m, __shfl_xor(m, off));
        float denom = 0.f;
        for (int j = row + lane; j < end; j += 64) {
            float ee = s_src[col[j]] + sdi;
            ee = (ee >= 0.f) ? ee : NEG_SLOPE * ee;
            denom += __expf(ee - m);
        }
#pragma unroll
        for (int off = 32; off >= 1; off >>= 1) denom += __shfl_xor(denom, off);
        float inv = 1.f / denom;
        float acc = 0.f;
        for (int j = row; j < end; ++j) {
            int cc = col[j];
            float ee = s_src[cc] + sdi;
            ee = (ee >= 0.f) ? ee : NEG_SLOPE * ee;
            unsigned hv = hWb[cc * 64 + lane];
            acc = fmaf(__expf(ee - m) * inv, blo(hv), acc);
        }
        float o = acc + bias[lane];
        if (mode == 0) {
            hout[node * 64 + lane] = f2bf(fmaxf(o, 0.f));
        } else {
            float p0 = o * W_out[lane * 2];
            float p1 = o * W_out[lane * 2 + 1];
#pragma unroll
            for (int off = 32; off >= 1; off >>= 1) {
                p0 += __shfl_xor(p0, off);
                p1 += __shfl_xor(p1, off);
            }
            if (lane == 0) {
                int g = batch[node];
                atomicAdd(&rep[g * 2], p0);
                atomicAdd(&rep[g * 2 + 1], p1);
            }
        }
    }
}

// ---------------- head: reduce replicas, divide by count, add b_out ----------------

__device__ __forceinline__ int lower_bound_dev(const int* __restrict__ a, int n, int v) {
    int lo = 0, hi = n;
    while (lo < hi) {
        int mid = (lo + hi) >> 1;
        if (a[mid] < v) lo = mid + 1; else hi = mid;
    }
    return lo;
}

__global__ void k_head(const float* __restrict__ pool_acc,
                       const int* __restrict__ batch,
                       const float* __restrict__ b_out,
                       float* __restrict__ out)
{
    int t = threadIdx.x;
    if (t < 2 * N_GRAPHS) {
        float s = 0.f;
#pragma unroll 8
        for (int r = 0; r < NREP; ++r) s += pool_acc[r * REP_STRIDE + t];
        int g = t >> 1, c = t & 1;
        int start = lower_bound_dev(batch, N_NODES, g);
        int end = lower_bound_dev(batch, N_NODES, g + 1);
        float cnt = fmaxf((float)(end - start), 1.f);
        out[t] = s / cnt + b_out[c];
    }
}

// ---------------- launch ----------------

extern "C" void kernel_launch(void* const* d_in, const int* in_sizes, int n_in,
                              void* d_out, int out_size, void* d_ws, size_t ws_size,
                              hipStream_t stream) {
    const int*   x       = (const int*)d_in[0];
    const int*   edge    = (const int*)d_in[1];   // [2][E]
    const int*   batch   = (const int*)d_in[2];
    const float* embed   = (const float*)d_in[3];
    const float* Ws      = (const float*)d_in[4];
    const float* a_srcs  = (const float*)d_in[5];
    const float* a_dsts  = (const float*)d_in[6];
    const float* biases  = (const float*)d_in[7];
    const float* W_out   = (const float*)d_in[8];
    const float* b_out   = (const float*)d_in[9];
    float* out = (float*)d_out;

    char* ws = (char*)d_ws;
    size_t off = 0;
    auto alloc = [&](size_t bytes) -> void* {
        void* p = ws + off;
        off += (bytes + 255) & ~(size_t)255;
        return p;
    };
    unsigned short* hbuf0  = (unsigned short*)alloc((size_t)N_NODES * 64 * sizeof(unsigned short)); // bf16 layer io
    unsigned short* hWb    = (unsigned short*)alloc((size_t)N_NODES * 64 * sizeof(unsigned short));
    float* s_src    = (float*)alloc((size_t)N_NODES * sizeof(float));
    float* s_dst    = (float*)alloc((size_t)N_NODES * sizeof(float));
    int*   rowptr   = (int*)alloc((size_t)(N_NODES + 1) * sizeof(int));
    int*   colA     = (int*)alloc((size_t)ETOT * sizeof(int));
    int*   blockcnt = (int*)alloc((size_t)PAIR_BLOCKS * NB * sizeof(int));
    int*   btot     = (int*)alloc((size_t)NB * sizeof(int));
    int*   pstart   = (int*)alloc((size_t)(NB + 1) * sizeof(int));
    float* pool_acc = (float*)alloc((size_t)(NREP * REP_STRIDE) * sizeof(float));
    int*   pairs    = (int*)alloc((size_t)N_EDGES * sizeof(int));  // dead after CSR build

    const int* e0 = edge;
    const int* e1 = edge + N_EDGES;

    // bucketed CSR build (by dst, self loops at slot 0 of each row)
    k_count<<<PAIR_BLOCKS, 256, 0, stream>>>(e1, blockcnt, pool_acc);
    k_scan_bases<<<NB, 64, 0, stream>>>(blockcnt, btot);
    k_scan_buckets<<<1, 128, 0, stream>>>(btot, pstart);
    k_pair_scatter<<<PAIR_BLOCKS, 256, 0, stream>>>(e0, e1, blockcnt, pstart, pairs);
    k_csr_bucket<<<NB, 1024, 0, stream>>>(pairs, pstart, rowptr, colA);

    const int gemm_blocks = (N_NODES + 63) / 64;
    const void* hin = nullptr;
    for (int l = 0; l < 3; ++l) {
        k_gemm_score<<<gemm_blocks, 256, 0, stream>>>(
            hin, x, embed, Ws + (size_t)l * 4096, a_srcs + l * 64, a_dsts + l * 64,
            hWb, s_src, s_dst, (l == 0) ? 1 : 0);
        k_agg<<<(N_NODES + 3) / 4, 256, 0, stream>>>(
            hWb, colA, rowptr, s_src, s_dst, biases + l * 64, hbuf0,
            (l < 2) ? 0 : 1, batch, W_out, pool_acc);
        hin = hbuf0;
    }
    k_head<<<1, 256, 0, stream>>>(pool_acc, batch, b_out, out);
}

// Round 8
// 364.533 us; speedup vs baseline: 2.9055x; 1.0178x over previous
//
#include <hip/hip_runtime.h>
#include <hip/hip_bf16.h>
#include <float.h>

#define N_NODES 100000
#define N_EDGES 1600000
#define HIDDEN 64
#define N_GRAPHS 128
#define NEG_SLOPE 0.2f
#define ETOT (N_EDGES + N_NODES)

#define BSHIFT 10
#define NB ((N_NODES + 1023) >> BSHIFT)   // 98 buckets of 1024 nodes
#define PAIR_CHUNK 4096
#define PAIR_BLOCKS ((N_EDGES + PAIR_CHUNK - 1) / PAIR_CHUNK)  // 391

#define NREP 64           // pool accumulator replicas (atomic contention spreading)
#define REP_STRIDE 272    // 256 floats + 16 pad

__device__ __forceinline__ unsigned short f2bf(float f) {
    unsigned u = __float_as_uint(f);
    unsigned r = (u + 0x7FFFu + ((u >> 16) & 1u)) >> 16;  // RNE
    return (unsigned short)r;
}
__device__ __forceinline__ float blo(unsigned u) { return __uint_as_float(u << 16); }
__device__ __forceinline__ float bhi(unsigned u) { return __uint_as_float(u & 0xFFFF0000u); }

// ---------------- CSR build: per-chunk bucket counts (also zeroes pool_acc) ----------------

__global__ __launch_bounds__(256) void k_count(const int* __restrict__ e1,
                                               int* __restrict__ blockcnt,
                                               float* __restrict__ pool_acc) {
    __shared__ int h[NB];
    int t = threadIdx.x, b = blockIdx.x;
    if (t < NB) h[t] = 0;
    if (b < NREP && t < 2 * N_GRAPHS) pool_acc[b * REP_STRIDE + t] = 0.f;
    __syncthreads();
    int ebase = b * PAIR_CHUNK;
    int ecount = min(PAIR_CHUNK, N_EDGES - ebase);
    for (int i = t; i < ecount; i += 256)
        atomicAdd(&h[e1[ebase + i] >> BSHIFT], 1);
    __syncthreads();
    if (t < NB) blockcnt[b * NB + t] = h[t];
}

// one wave per bucket: exclusive scan over its chunk counts (in place) + total
__global__ __launch_bounds__(64) void k_scan_bases(int* __restrict__ blockcnt,
                                                   int* __restrict__ btot) {
    int b = blockIdx.x;
    int lane = threadIdx.x;
    int s = 0;
    for (int base = 0; base < PAIR_BLOCKS; base += 64) {
        int c = base + lane;
        int v = (c < PAIR_BLOCKS) ? blockcnt[c * NB + b] : 0;
        int xv = v;
#pragma unroll
        for (int off = 1; off < 64; off <<= 1) {
            int y = __shfl_up(xv, off);
            if (lane >= off) xv += y;
        }
        if (c < PAIR_BLOCKS) blockcnt[c * NB + b] = s + xv - v;
        s += __shfl(xv, 63);
    }
    if (lane == 0) btot[b] = s;
}

__global__ void k_scan_buckets(const int* __restrict__ btot, int* __restrict__ pair_start) {
    __shared__ int tot[128];
    int t = threadIdx.x;
    int v = (t < NB) ? btot[t] : 0;
    tot[t] = v;
    __syncthreads();
    for (int off = 1; off < 128; off <<= 1) {
        int u = (t >= off) ? tot[t - off] : 0;
        __syncthreads();
        tot[t] += u;
        __syncthreads();
    }
    if (t < NB) pair_start[t] = tot[t] - v;
    if (t == 0) pair_start[NB] = N_EDGES;
}

__global__ __launch_bounds__(256) void k_pair_scatter(
    const int* __restrict__ e0, const int* __restrict__ e1,
    const int* __restrict__ blockcnt, const int* __restrict__ pair_start,
    int* __restrict__ pairs)
{
    __shared__ int cnt[NB];
    __shared__ int base[NB];
    int t = threadIdx.x, b = blockIdx.x;
    if (t < NB) {
        cnt[t] = 0;
        base[t] = pair_start[t] + blockcnt[b * NB + t];
    }
    __syncthreads();
    int ebase = b * PAIR_CHUNK;
    int ecount = min(PAIR_CHUNK, N_EDGES - ebase);
    for (int i = t; i < ecount; i += 256) {
        int s = e0[ebase + i];
        int d = e1[ebase + i];
        int B = d >> BSHIFT;
        int idx = atomicAdd(&cnt[B], 1);
        pairs[base[B] + idx] = ((d & 1023) << 17) | s;   // 10b local dst | 17b src
    }
}

// One block per bucket: local degree histogram + wave-scan + col scatter in LDS.
// Self loop occupies slot 0 of each row.
__global__ __launch_bounds__(1024) void k_csr_bucket(
    const int* __restrict__ pairs, const int* __restrict__ pair_start,
    int* __restrict__ rowptr, int* __restrict__ col)
{
    __shared__ int deg[1024];
    __shared__ int excl[1024];
    __shared__ int wsum[16];
    int b = blockIdx.x;
    int t = threadIdx.x;
    int nb = b << BSHIFT;
    int nodes = min(1024, N_NODES - nb);

    deg[t] = (t < nodes) ? 1 : 0;   // self loop
    __syncthreads();
    int p0 = pair_start[b], p1 = pair_start[b + 1];
    for (int i = p0 + t; i < p1; i += 1024)
        atomicAdd(&deg[pairs[i] >> 17], 1);
    __syncthreads();

    int val = deg[t];
    int x = val;
#pragma unroll
    for (int off = 1; off < 64; off <<= 1) {
        int y = __shfl_up(x, off);
        if ((t & 63) >= off) x += y;
    }
    if ((t & 63) == 63) wsum[t >> 6] = x;
    __syncthreads();
    if (t == 0) {
        int s = 0;
#pragma unroll
        for (int i = 0; i < 16; ++i) { int v = wsum[i]; wsum[i] = s; s += v; }
    }
    __syncthreads();
    int ex = x - val + wsum[t >> 6];  // exclusive prefix of local degrees
    excl[t] = ex;

    int colbase = p0 + nb;  // nb == #self-loops in preceding buckets
    if (t < nodes) {
        rowptr[nb + t] = colbase + ex;
        col[colbase + ex] = nb + t;  // self loop at slot 0
    }
    if (b == NB - 1 && t == 0) rowptr[N_NODES] = ETOT;

    deg[t] = 1;  // slot 0 taken by self loop
    __syncthreads();
    for (int i = p0 + t; i < p1; i += 1024) {
        int p = pairs[i];
        int li = p >> 17;
        int pos = colbase + excl[li] + atomicAdd(&deg[li], 1);
        col[pos] = p & 0x1FFFF;
    }
}

// ---------------- layer-0 GEMM + attention scores (from embeddings) ----------------

__global__ __launch_bounds__(256) void k_gemm_score(
    const int* __restrict__ x, const float* __restrict__ embed,
    const float* __restrict__ W, const float* __restrict__ a_s,
    const float* __restrict__ a_d, unsigned short* __restrict__ hWb,
    float* __restrict__ s_src, float* __restrict__ s_dst)
{
    __shared__ float Wl[64 * 64];
    __shared__ float hT[64 * 68];  // [k][r], pitch 68
    int t = threadIdx.x;
    int r0 = blockIdx.x * 64;

    for (int i = t; i < 4096; i += 256) Wl[i] = W[i];
    for (int i = t; i < 4096; i += 256) {
        int r = i >> 6, k = i & 63;
        int row = r0 + r;
        float v = (row < N_NODES) ? embed[x[row] * 64 + k] : 0.f;
        hT[k * 68 + r] = v;
    }
    __syncthreads();

    int tcol = t & 15;
    int trow = t >> 4;
    float acc[4][4];
#pragma unroll
    for (int i = 0; i < 4; ++i)
#pragma unroll
        for (int j = 0; j < 4; ++j) acc[i][j] = 0.f;

    for (int k = 0; k < 64; ++k) {
        float4 va = *(const float4*)&hT[k * 68 + trow * 4];
        float4 vb = *(const float4*)&Wl[k * 64 + tcol * 4];
        float a[4] = {va.x, va.y, va.z, va.w};
        float bb[4] = {vb.x, vb.y, vb.z, vb.w};
#pragma unroll
        for (int i = 0; i < 4; ++i)
#pragma unroll
            for (int j = 0; j < 4; ++j) acc[i][j] = fmaf(a[i], bb[j], acc[i][j]);
    }

    float4 as4 = *(const float4*)&a_s[tcol * 4];
    float4 ad4 = *(const float4*)&a_d[tcol * 4];
    float asr[4] = {as4.x, as4.y, as4.z, as4.w};
    float adr[4] = {ad4.x, ad4.y, ad4.z, ad4.w};

#pragma unroll
    for (int i = 0; i < 4; ++i) {
        int row = r0 + trow * 4 + i;
        float ps = 0.f, pd = 0.f;
#pragma unroll
        for (int j = 0; j < 4; ++j) {
            ps = fmaf(acc[i][j], asr[j], ps);
            pd = fmaf(acc[i][j], adr[j], pd);
        }
#pragma unroll
        for (int off = 8; off >= 1; off >>= 1) {
            ps += __shfl_xor(ps, off);
            pd += __shfl_xor(pd, off);
        }
        if (row < N_NODES) {
            ushort4 o;
            o.x = f2bf(acc[i][0]); o.y = f2bf(acc[i][1]);
            o.z = f2bf(acc[i][2]); o.w = f2bf(acc[i][3]);
            *(ushort4*)&hWb[row * 64 + tcol * 4] = o;
            if (tcol == 0) { s_src[row] = ps; s_dst[row] = pd; }
        }
    }
}

// ---------------- fused agg + next-layer GEMM + next scores (layers 0,1) ----------------
// Grid-stride persistent blocks; W' (next layer weight) staged in LDS once per block.
// Gather: quarter-wave (16 lanes x uint2 = 128-B bf16 row), 16 edges per 4-load iter.
// Epilogue: o = relu(agg+bias) staged in LDS; each lane computes one column of o@W',
// writes hWb_out (bf16) + s_src/s_dst_out.

__global__ __launch_bounds__(256) void k_agg_fused(
    const unsigned short* __restrict__ hWb_in, const int* __restrict__ col,
    const int* __restrict__ rowptr, const float* __restrict__ s_src_in,
    const float* __restrict__ s_dst_in, const float* __restrict__ bias,
    const float* __restrict__ Wn, const float* __restrict__ a_s_n,
    const float* __restrict__ a_d_n, unsigned short* __restrict__ hWb_out,
    float* __restrict__ s_src_out, float* __restrict__ s_dst_out)
{
    __shared__ float Wl[64 * 64];    // next-layer weight
    __shared__ float2 stash[4][64];  // (p, row byte-offset bits)
    __shared__ float oSt[4][64];     // per-wave activation staging
    int t = threadIdx.x;
    for (int i = t; i < 4096; i += 256) Wl[i] = Wn[i];
    __syncthreads();

    int wave = t >> 6;
    int lane = t & 63;
    const char* hb = (const char*)hWb_in;
    float asl = a_s_n[lane], adl = a_d_n[lane];

    for (int node = blockIdx.x * 4 + wave; node < N_NODES; node += gridDim.x * 4) {
        int row = rowptr[node];
        int end = rowptr[node + 1];
        int deg = end - row;
        float sdi = s_dst_in[node];

        if (deg <= 64) {
            int c = 0;
            float p = 0.f;
            if (lane < deg) {
                c = col[row + lane];
                float ee = s_src_in[c] + sdi;
                ee = (ee >= 0.f) ? ee : NEG_SLOPE * ee;
                p = __expf(ee);   // no max-sub: |e| small, fp32-safe
            }
            stash[wave][lane] = make_float2(p, __int_as_float(c * 128));

            int q = lane >> 4;
            int f = lane & 15;
            int f8 = f * 8;
            float acc0 = 0.f, acc1 = 0.f, acc2 = 0.f, acc3 = 0.f;
            int degr = (deg + 15) & ~15;
            for (int j = q; j < degr; j += 16) {
                float2 a0 = stash[wave][j];
                float2 a1 = stash[wave][j + 4];
                float2 a2 = stash[wave][j + 8];
                float2 a3 = stash[wave][j + 12];
                uint2 v0 = *(const uint2*)(hb + (__float_as_int(a0.y) + f8));
                uint2 v1 = *(const uint2*)(hb + (__float_as_int(a1.y) + f8));
                uint2 v2 = *(const uint2*)(hb + (__float_as_int(a2.y) + f8));
                uint2 v3 = *(const uint2*)(hb + (__float_as_int(a3.y) + f8));
                acc0 = fmaf(a0.x, blo(v0.x), acc0);
                acc1 = fmaf(a0.x, bhi(v0.x), acc1);
                acc2 = fmaf(a0.x, blo(v0.y), acc2);
                acc3 = fmaf(a0.x, bhi(v0.y), acc3);
                acc0 = fmaf(a1.x, blo(v1.x), acc0);
                acc1 = fmaf(a1.x, bhi(v1.x), acc1);
                acc2 = fmaf(a1.x, blo(v1.y), acc2);
                acc3 = fmaf(a1.x, bhi(v1.y), acc3);
                acc0 = fmaf(a2.x, blo(v2.x), acc0);
                acc1 = fmaf(a2.x, bhi(v2.x), acc1);
                acc2 = fmaf(a2.x, blo(v2.y), acc2);
                acc3 = fmaf(a2.x, bhi(v2.y), acc3);
                acc0 = fmaf(a3.x, blo(v3.x), acc0);
                acc1 = fmaf(a3.x, bhi(v3.x), acc1);
                acc2 = fmaf(a3.x, blo(v3.y), acc2);
                acc3 = fmaf(a3.x, bhi(v3.y), acc3);
            }
            float denom = p;
#pragma unroll
            for (int off = 32; off >= 1; off >>= 1) denom += __shfl_xor(denom, off);
            float inv = 1.f / denom;
            acc0 += __shfl_xor(acc0, 16); acc0 += __shfl_xor(acc0, 32);
            acc1 += __shfl_xor(acc1, 16); acc1 += __shfl_xor(acc1, 32);
            acc2 += __shfl_xor(acc2, 16); acc2 += __shfl_xor(acc2, 32);
            acc3 += __shfl_xor(acc3, 16); acc3 += __shfl_xor(acc3, 32);
            if (lane < 16) {
                float4 bb = *(const float4*)&bias[4 * f];
                float4 o4;
                o4.x = fmaxf(fmaf(acc0, inv, bb.x), 0.f);
                o4.y = fmaxf(fmaf(acc1, inv, bb.y), 0.f);
                o4.z = fmaxf(fmaf(acc2, inv, bb.z), 0.f);
                o4.w = fmaxf(fmaf(acc3, inv, bb.w), 0.f);
                *(float4*)&oSt[wave][4 * f] = o4;
            }
        } else {
            // generic path (deg > 64): statistically never hit
            float m = -FLT_MAX;
            for (int j = row + lane; j < end; j += 64) {
                float ee = s_src_in[col[j]] + sdi;
                ee = (ee >= 0.f) ? ee : NEG_SLOPE * ee;
                m = fmaxf(m, ee);
            }
#pragma unroll
            for (int off = 32; off >= 1; off >>= 1) m = fmaxf(m, __shfl_xor(m, off));
            float denom = 0.f;
            for (int j = row + lane; j < end; j += 64) {
                float ee = s_src_in[col[j]] + sdi;
                ee = (ee >= 0.f) ? ee : NEG_SLOPE * ee;
                denom += __expf(ee - m);
            }
#pragma unroll
            for (int off = 32; off >= 1; off >>= 1) denom += __shfl_xor(denom, off);
            float inv = 1.f / denom;
            float acc = 0.f;
            for (int j = row; j < end; ++j) {
                int cc = col[j];
                float ee = s_src_in[cc] + sdi;
                ee = (ee >= 0.f) ? ee : NEG_SLOPE * ee;
                unsigned hv = hWb_in[cc * 64 + lane];
                acc = fmaf(__expf(ee - m) * inv, blo(hv), acc);
            }
            oSt[wave][lane] = fmaxf(acc + bias[lane], 0.f);
        }

        // column GEMM: r = o @ Wn (this lane's column = lane)
        float r = 0.f;
#pragma unroll
        for (int qq = 0; qq < 16; ++qq) {
            float4 o4 = *(const float4*)&oSt[wave][4 * qq];
            r = fmaf(o4.x, Wl[(4 * qq + 0) * 64 + lane], r);
            r = fmaf(o4.y, Wl[(4 * qq + 1) * 64 + lane], r);
            r = fmaf(o4.z, Wl[(4 * qq + 2) * 64 + lane], r);
            r = fmaf(o4.w, Wl[(4 * qq + 3) * 64 + lane], r);
        }
        float ss = r * asl, sd = r * adl;
#pragma unroll
        for (int off = 32; off >= 1; off >>= 1) {
            ss += __shfl_xor(ss, off);
            sd += __shfl_xor(sd, off);
        }
        hWb_out[node * 64 + lane] = f2bf(r);
        if (lane == 0) { s_src_out[node] = ss; s_dst_out[node] = sd; }
    }
}

// ---------------- last-layer agg + pool projection ----------------

__global__ __launch_bounds__(256) void k_agg_pool(
    const unsigned short* __restrict__ hWb_in, const int* __restrict__ col,
    const int* __restrict__ rowptr, const float* __restrict__ s_src_in,
    const float* __restrict__ s_dst_in, const float* __restrict__ bias,
    const int* __restrict__ batch, const float* __restrict__ W_out,
    float* __restrict__ pool_acc)
{
    __shared__ float2 stash[4][64];
    int wave = threadIdx.x >> 6;
    int lane = threadIdx.x & 63;
    int node = blockIdx.x * 4 + wave;
    if (node >= N_NODES) return;

    int row = rowptr[node];
    int end = rowptr[node + 1];
    int deg = end - row;
    float sdi = s_dst_in[node];
    float* rep = pool_acc + (blockIdx.x & (NREP - 1)) * REP_STRIDE;
    const char* hb = (const char*)hWb_in;

    if (deg <= 64) {
        int c = 0;
        float p = 0.f;
        if (lane < deg) {
            c = col[row + lane];
            float ee = s_src_in[c] + sdi;
            ee = (ee >= 0.f) ? ee : NEG_SLOPE * ee;
            p = __expf(ee);
        }
        stash[wave][lane] = make_float2(p, __int_as_float(c * 128));

        int q = lane >> 4;
        int f = lane & 15;
        int f8 = f * 8;
        float acc0 = 0.f, acc1 = 0.f, acc2 = 0.f, acc3 = 0.f;
        int degr = (deg + 15) & ~15;
        for (int j = q; j < degr; j += 16) {
            float2 a0 = stash[wave][j];
            float2 a1 = stash[wave][j + 4];
            float2 a2 = stash[wave][j + 8];
            float2 a3 = stash[wave][j + 12];
            uint2 v0 = *(const uint2*)(hb + (__float_as_int(a0.y) + f8));
            uint2 v1 = *(const uint2*)(hb + (__float_as_int(a1.y) + f8));
            uint2 v2 = *(const uint2*)(hb + (__float_as_int(a2.y) + f8));
            uint2 v3 = *(const uint2*)(hb + (__float_as_int(a3.y) + f8));
            acc0 = fmaf(a0.x, blo(v0.x), acc0);
            acc1 = fmaf(a0.x, bhi(v0.x), acc1);
            acc2 = fmaf(a0.x, blo(v0.y), acc2);
            acc3 = fmaf(a0.x, bhi(v0.y), acc3);
            acc0 = fmaf(a1.x, blo(v1.x), acc0);
            acc1 = fmaf(a1.x, bhi(v1.x), acc1);
            acc2 = fmaf(a1.x, blo(v1.y), acc2);
            acc3 = fmaf(a1.x, bhi(v1.y), acc3);
            acc0 = fmaf(a2.x, blo(v2.x), acc0);
            acc1 = fmaf(a2.x, bhi(v2.x), acc1);
            acc2 = fmaf(a2.x, blo(v2.y), acc2);
            acc3 = fmaf(a2.x, bhi(v2.y), acc3);
            acc0 = fmaf(a3.x, blo(v3.x), acc0);
            acc1 = fmaf(a3.x, bhi(v3.x), acc1);
            acc2 = fmaf(a3.x, blo(v3.y), acc2);
            acc3 = fmaf(a3.x, bhi(v3.y), acc3);
        }
        float denom = p;
#pragma unroll
        for (int off = 32; off >= 1; off >>= 1) denom += __shfl_xor(denom, off);
        float inv = 1.f / denom;
        acc0 += __shfl_xor(acc0, 16); acc0 += __shfl_xor(acc0, 32);
        acc1 += __shfl_xor(acc1, 16); acc1 += __shfl_xor(acc1, 32);
        acc2 += __shfl_xor(acc2, 16); acc2 += __shfl_xor(acc2, 32);
        acc3 += __shfl_xor(acc3, 16); acc3 += __shfl_xor(acc3, 32);

        float4 bb = *(const float4*)&bias[4 * f];
        float o0 = fmaf(acc0, inv, bb.x), o1 = fmaf(acc1, inv, bb.y);
        float o2 = fmaf(acc2, inv, bb.z), o3 = fmaf(acc3, inv, bb.w);
        float4 wa = *(const float4*)&W_out[8 * f];      // rows 4f, 4f+1
        float4 wb = *(const float4*)&W_out[8 * f + 4];  // rows 4f+2, 4f+3
        float p0 = o0 * wa.x + o1 * wa.z + o2 * wb.x + o3 * wb.z;
        float p1 = o0 * wa.y + o1 * wa.w + o2 * wb.y + o3 * wb.w;
#pragma unroll
        for (int off = 8; off >= 1; off >>= 1) {
            p0 += __shfl_xor(p0, off);
            p1 += __shfl_xor(p1, off);
        }
        if (lane == 0) {
            int g = batch[node];
            atomicAdd(&rep[g * 2], p0);
            atomicAdd(&rep[g * 2 + 1], p1);
        }
    } else {
        float m = -FLT_MAX;
        for (int j = row + lane; j < end; j += 64) {
            float ee = s_src_in[col[j]] + sdi;
            ee = (ee >= 0.f) ? ee : NEG_SLOPE * ee;
            m = fmaxf(m, ee);
        }
#pragma unroll
        for (int off = 32; off >= 1; off >>= 1) m = fmaxf(m, __shfl_xor(m, off));
        float denom = 0.f;
        for (int j = row + lane; j < end; j += 64) {
            float ee = s_src_in[col[j]] + sdi;
            ee = (ee >= 0.f) ? ee : NEG_SLOPE * ee;
            denom += __expf(ee - m);
        }
#pragma unroll
        for (int off = 32; off >= 1; off >>= 1) denom += __shfl_xor(denom, off);
        float inv = 1.f / denom;
        float acc = 0.f;
        for (int j = row; j < end; ++j) {
            int cc = col[j];
            float ee = s_src_in[cc] + sdi;
            ee = (ee >= 0.f) ? ee : NEG_SLOPE * ee;
            unsigned hv = hWb_in[cc * 64 + lane];
            acc = fmaf(__expf(ee - m) * inv, blo(hv), acc);
        }
        float o = acc + bias[lane];
        float p0 = o * W_out[lane * 2];
        float p1 = o * W_out[lane * 2 + 1];
#pragma unroll
        for (int off = 32; off >= 1; off >>= 1) {
            p0 += __shfl_xor(p0, off);
            p1 += __shfl_xor(p1, off);
        }
        if (lane == 0) {
            int g = batch[node];
            atomicAdd(&rep[g * 2], p0);
            atomicAdd(&rep[g * 2 + 1], p1);
        }
    }
}

// ---------------- head: reduce replicas, divide by count, add b_out ----------------

__device__ __forceinline__ int lower_bound_dev(const int* __restrict__ a, int n, int v) {
    int lo = 0, hi = n;
    while (lo < hi) {
        int mid = (lo + hi) >> 1;
        if (a[mid] < v) lo = mid + 1; else hi = mid;
    }
    return lo;
}

__global__ void k_head(const float* __restrict__ pool_acc,
                       const int* __restrict__ batch,
                       const float* __restrict__ b_out,
                       float* __restrict__ out)
{
    int t = threadIdx.x;
    if (t < 2 * N_GRAPHS) {
        float s = 0.f;
#pragma unroll 8
        for (int r = 0; r < NREP; ++r) s += pool_acc[r * REP_STRIDE + t];
        int g = t >> 1, c = t & 1;
        int start = lower_bound_dev(batch, N_NODES, g);
        int end = lower_bound_dev(batch, N_NODES, g + 1);
        float cnt = fmaxf((float)(end - start), 1.f);
        out[t] = s / cnt + b_out[c];
    }
}

// ---------------- launch ----------------

extern "C" void kernel_launch(void* const* d_in, const int* in_sizes, int n_in,
                              void* d_out, int out_size, void* d_ws, size_t ws_size,
                              hipStream_t stream) {
    const int*   x       = (const int*)d_in[0];
    const int*   edge    = (const int*)d_in[1];   // [2][E]
    const int*   batch   = (const int*)d_in[2];
    const float* embed   = (const float*)d_in[3];
    const float* Ws      = (const float*)d_in[4];
    const float* a_srcs  = (const float*)d_in[5];
    const float* a_dsts  = (const float*)d_in[6];
    const float* biases  = (const float*)d_in[7];
    const float* W_out   = (const float*)d_in[8];
    const float* b_out   = (const float*)d_in[9];
    float* out = (float*)d_out;

    char* ws = (char*)d_ws;
    size_t off = 0;
    auto alloc = [&](size_t bytes) -> void* {
        void* p = ws + off;
        off += (bytes + 255) & ~(size_t)255;
        return p;
    };
    unsigned short* hA     = (unsigned short*)alloc((size_t)N_NODES * 64 * sizeof(unsigned short));
    unsigned short* hB     = (unsigned short*)alloc((size_t)N_NODES * 64 * sizeof(unsigned short));
    float* s_src0   = (float*)alloc((size_t)N_NODES * sizeof(float));
    float* s_dst0   = (float*)alloc((size_t)N_NODES * sizeof(float));
    float* s_src1   = (float*)alloc((size_t)N_NODES * sizeof(float));
    float* s_dst1   = (float*)alloc((size_t)N_NODES * sizeof(float));
    int*   rowptr   = (int*)alloc((size_t)(N_NODES + 1) * sizeof(int));
    int*   colA     = (int*)alloc((size_t)ETOT * sizeof(int));
    int*   blockcnt = (int*)alloc((size_t)PAIR_BLOCKS * NB * sizeof(int));
    int*   btot     = (int*)alloc((size_t)NB * sizeof(int));
    int*   pstart   = (int*)alloc((size_t)(NB + 1) * sizeof(int));
    float* pool_acc = (float*)alloc((size_t)(NREP * REP_STRIDE) * sizeof(float));
    int*   pairs    = (int*)alloc((size_t)N_EDGES * sizeof(int));  // dead after CSR build

    const int* e0 = edge;
    const int* e1 = edge + N_EDGES;

    // bucketed CSR build (by dst, self loops at slot 0 of each row)
    k_count<<<PAIR_BLOCKS, 256, 0, stream>>>(e1, blockcnt, pool_acc);
    k_scan_bases<<<NB, 64, 0, stream>>>(blockcnt, btot);
    k_scan_buckets<<<1, 128, 0, stream>>>(btot, pstart);
    k_pair_scatter<<<PAIR_BLOCKS, 256, 0, stream>>>(e0, e1, blockcnt, pstart, pairs);
    k_csr_bucket<<<NB, 1024, 0, stream>>>(pairs, pstart, rowptr, colA);

    const int gemm_blocks = (N_NODES + 63) / 64;
    // layer 0 GEMM from embeddings
    k_gemm_score<<<gemm_blocks, 256, 0, stream>>>(
        x, embed, Ws, a_srcs, a_dsts, hA, s_src0, s_dst0);
    // layer 0 agg fused with layer-1 GEMM+scores
    k_agg_fused<<<2048, 256, 0, stream>>>(
        hA, colA, rowptr, s_src0, s_dst0, biases,
        Ws + 4096, a_srcs + 64, a_dsts + 64, hB, s_src1, s_dst1);
    // layer 1 agg fused with layer-2 GEMM+scores
    k_agg_fused<<<2048, 256, 0, stream>>>(
        hB, colA, rowptr, s_src1, s_dst1, biases + 64,
        Ws + 8192, a_srcs + 128, a_dsts + 128, hA, s_src0, s_dst0);
    // layer 2 agg + pool projection
    k_agg_pool<<<(N_NODES + 3) / 4, 256, 0, stream>>>(
        hA, colA, rowptr, s_src0, s_dst0, biases + 128, batch, W_out, pool_acc);
    k_head<<<1, 256, 0, stream>>>(pool_acc, batch, b_out, out);
}